// Round 2
// baseline (1832.726 us; speedup 1.0000x reference)
//
#include <hip/hip_runtime.h>
#include <stdint.h>

#define DM     2048
#define NHE    16
#define DFF    8192
#define NBATCH 2
#define SEQ    2048
#define NTOK   4096
#define HD     128
#define NVOCAB 32000

typedef __attribute__((ext_vector_type(8))) short short8;
typedef __attribute__((ext_vector_type(4))) float f32x4;
typedef __attribute__((ext_vector_type(4))) unsigned short u16x4;

static __device__ __forceinline__ unsigned short f2b(float f) {
  union { float f; uint32_t u; } v; v.f = f;
  return (unsigned short)((v.u + 0x7FFFu + ((v.u >> 16) & 1u)) >> 16);
}

static __device__ __forceinline__ void gload16(const void* g, void* l) {
  __builtin_amdgcn_global_load_lds(
      (const __attribute__((address_space(1))) unsigned int*)g,
      (__attribute__((address_space(3))) unsigned int*)l, 16, 0, 0);
}

// ---------------------------------------------------------------- conversions
__global__ void k_f32_to_bf16(const float* __restrict__ in,
                              unsigned short* __restrict__ out, int nq) {
  int i = blockIdx.x * blockDim.x + threadIdx.x;
  int stride = gridDim.x * blockDim.x;
  for (; i < nq; i += stride) {
    float4 v = ((const float4*)in)[i];
    u16x4 o;
    o.x = f2b(v.x); o.y = f2b(v.y); o.z = f2b(v.z); o.w = f2b(v.w);
    ((u16x4*)out)[i] = o;
  }
}

// ---------------------------------------------------------------- embedding
__global__ void k_embed(const int* __restrict__ tok,
                        const float* __restrict__ emb, float* __restrict__ x) {
  int n = blockIdx.x;
  int t = tok[n];
  const float4* src = (const float4*)(emb + (size_t)t * DM);
  float4* dst = (float4*)(x + (size_t)n * DM);
  for (int i = threadIdx.x; i < DM / 4; i += blockDim.x) dst[i] = src[i];
}

// ---------------------------------------------------------------- rmsnorm
__global__ void k_rmsnorm(const float* __restrict__ x, const float* __restrict__ wt,
                          unsigned short* __restrict__ out) {
  int n = blockIdx.x;
  const float* row = x + (size_t)n * DM;
  float ss = 0.f;
  #pragma unroll
  for (int it = 0; it < 2; ++it) {
    int i = threadIdx.x * 4 + it * 1024;
    float4 v = *(const float4*)(row + i);
    ss += v.x * v.x + v.y * v.y + v.z * v.z + v.w * v.w;
  }
  #pragma unroll
  for (int m = 1; m < 64; m <<= 1) ss += __shfl_xor(ss, m);
  __shared__ float p[4];
  if ((threadIdx.x & 63) == 0) p[threadIdx.x >> 6] = ss;
  __syncthreads();
  float inv = rsqrtf((p[0] + p[1] + p[2] + p[3]) * (1.f / DM) + 1e-6f);
  #pragma unroll
  for (int it = 0; it < 2; ++it) {
    int i = threadIdx.x * 4 + it * 1024;
    float4 v = *(const float4*)(row + i);
    float4 w4 = *(const float4*)(wt + i);
    u16x4 o;
    o.x = f2b(v.x * w4.x * inv); o.y = f2b(v.y * w4.y * inv);
    o.z = f2b(v.z * w4.z * inv); o.w = f2b(v.w * w4.w * inv);
    *(u16x4*)(out + (size_t)n * DM + i) = o;
  }
}

// ---------------------------------------------------------------- GEMM (NT)
// C[M,N] = A[M,K] * B[N,K]^T ; A,B bf16 row-major K-contig; f32 accum.
// 128x128 tile, BK=64, 4 waves (2x2), 4x4 16x16x32 frags per wave.
// bn-major block order within XCD chunk: B-tile stays L2-resident.
#define EPI_BF16  0
#define EPI_RESID 1
#define EPI_SILU  2
#define EPI_F32   3

template <int EPI>
__launch_bounds__(256)
__global__ void k_gemm_nt(const unsigned short* __restrict__ A,
                          const unsigned short* __restrict__ Bm,
                          int M, int N, int K,
                          float* __restrict__ Cf, unsigned short* __restrict__ Cb,
                          const float* __restrict__ R) {
  __shared__ unsigned short a_lds[128 * 64];
  __shared__ unsigned short b_lds[128 * 64];
  int nbm = M >> 7;
  int nwg = gridDim.x;
  int bid = blockIdx.x;
  int cpx = nwg >> 3;                       // all grids are multiples of 8
  bid = (bid & 7) * cpx + (bid >> 3);       // XCD-bijective swizzle
  int bn = bid / nbm, bm = bid % nbm;       // bn-major: B-tile reuse in L2
  int t = threadIdx.x, w = t >> 6, lane = t & 63;
  int wr = w >> 1, wc = w & 1;
  int g = lane >> 4, l15 = lane & 15;

  f32x4 acc[4][4] = {};

  size_t abase = (size_t)(bm * 128) * K;
  size_t bbase = (size_t)(bn * 128) * K;
  int nkt = K >> 6;

  for (int kt = 0; kt < nkt; ++kt) {
    int k0 = kt << 6;
    #pragma unroll
    for (int i = 0; i < 4; ++i) {
      int pos = ((i * 4 + w) << 10) + lane * 16;   // byte pos in 16KB tile
      int row = pos >> 7;
      int csw = pos & 127;
      int csrc = csw ^ ((row & 7) << 4);
      char* ldst_a = (char*)a_lds + ((i * 4 + w) << 10);
      char* ldst_b = (char*)b_lds + ((i * 4 + w) << 10);
      gload16(A + abase + (size_t)row * K + k0 + (csrc >> 1), ldst_a);
      gload16(Bm + bbase + (size_t)row * K + k0 + (csrc >> 1), ldst_b);
    }
    __syncthreads();
    #pragma unroll
    for (int kk = 0; kk < 2; ++kk) {
      short8 af[4], bfr[4];
      #pragma unroll
      for (int mm = 0; mm < 4; ++mm) {
        int row = wr * 64 + mm * 16 + l15;
        int col = kk * 64 + g * 16;
        af[mm] = *(const short8*)((const char*)a_lds + row * 128 + (col ^ ((row & 7) << 4)));
      }
      #pragma unroll
      for (int nn = 0; nn < 4; ++nn) {
        int row = wc * 64 + nn * 16 + l15;
        int col = kk * 64 + g * 16;
        bfr[nn] = *(const short8*)((const char*)b_lds + row * 128 + (col ^ ((row & 7) << 4)));
      }
      #pragma unroll
      for (int mm = 0; mm < 4; ++mm)
        #pragma unroll
        for (int nn = 0; nn < 4; ++nn)
          acc[mm][nn] = __builtin_amdgcn_mfma_f32_16x16x32_bf16(af[mm], bfr[nn], acc[mm][nn], 0, 0, 0);
    }
    __syncthreads();
  }

  #pragma unroll
  for (int mm = 0; mm < 4; ++mm) {
    #pragma unroll
    for (int nn = 0; nn < 4; ++nn) {
      #pragma unroll
      for (int r = 0; r < 4; ++r) {
        int grow = bm * 128 + wr * 64 + mm * 16 + g * 4 + r;
        int gcol = bn * 128 + wc * 64 + nn * 16 + l15;
        size_t off = (size_t)grow * N + gcol;
        float v = acc[mm][nn][r];
        if (EPI == EPI_BF16) {
          Cb[off] = f2b(v);
        } else if (EPI == EPI_RESID) {
          Cf[off] = R[off] + v;
        } else if (EPI == EPI_SILU) {
          float s = 1.f / (1.f + __expf(-v));
          Cb[off] = f2b(v * s);
        } else {
          Cf[off] = v;
        }
      }
    }
  }
}

// ---------------------------------------------------------------- V transpose
// v rows (stride vstride) -> vt [32 pairs][HD][SEQ] bf16
__global__ void k_transpose_v(const unsigned short* __restrict__ v, int vstride,
                              unsigned short* __restrict__ vt) {
  __shared__ unsigned short tile[64][136];
  int pr = blockIdx.x >> 5;     // pair
  int st = blockIdx.x & 31;     // s-tile of 64
  int bb = pr >> 4, h = pr & 15;
  int row = threadIdx.x >> 2;   // 0..63 (s within tile)
  int cq = threadIdx.x & 3;
  const unsigned short* src =
      v + (size_t)(bb * SEQ + st * 64 + row) * vstride + h * HD + cq * 32;
  #pragma unroll
  for (int j = 0; j < 4; ++j)
    *(short8*)&tile[row][cq * 32 + j * 8] = *(const short8*)(src + j * 8);
  __syncthreads();
  int d = threadIdx.x >> 1;     // 0..127
  int sh = threadIdx.x & 1;     // s-half of 32
  unsigned short tmp[32];
  #pragma unroll
  for (int j = 0; j < 32; ++j) tmp[j] = tile[sh * 32 + j][d];
  unsigned short* dst = vt + ((size_t)pr * HD + d) * SEQ + st * 64 + sh * 32;
  #pragma unroll
  for (int j = 0; j < 4; ++j)
    *(short8*)(dst + j * 8) = *(const short8*)&tmp[j * 8];
}

// ---------------------------------------------------------------- attention
__launch_bounds__(256)
__global__ void k_attn(const unsigned short* __restrict__ q,
                       const unsigned short* __restrict__ k,
                       const unsigned short* __restrict__ vt,
                       unsigned short* __restrict__ ao, int qk_stride) {
  __shared__ unsigned short k_lds[64 * 128];
  __shared__ unsigned short vt_lds[128 * 64];
  __shared__ unsigned short p_lds[4][32 * 64];

  int bid = blockIdx.x;
  int pr = bid >> 4;
  int qt = 15 - (bid & 15);          // heavy tiles first
  int bb = pr >> 4, h = pr & 15;
  int t = threadIdx.x, w = t >> 6, lane = t & 63;
  int g = lane >> 4, l15 = lane & 15;
  const float SCL = 0.08838834764831845f * 1.4426950408889634f; // 1/sqrt(128)*log2e

  int qrow_base = qt * 128 + w * 32;
  short8 aq[2][4];
  #pragma unroll
  for (int mm = 0; mm < 2; ++mm) {
    size_t n = (size_t)(bb * SEQ + qrow_base + mm * 16 + l15);
    #pragma unroll
    for (int kk = 0; kk < 4; ++kk)
      aq[mm][kk] = *(const short8*)(q + n * qk_stride + h * HD + kk * 32 + g * 8);
  }

  f32x4 o[2][8] = {};
  float m2[2][4], ls[2][4];
  #pragma unroll
  for (int mm = 0; mm < 2; ++mm)
    #pragma unroll
    for (int r = 0; r < 4; ++r) { m2[mm][r] = -1e30f; ls[mm][r] = 0.f; }

  int nkv = 2 * qt + 2;
  for (int kvt = 0; kvt < nkv; ++kvt) {
    // ---- stage K and VT tiles (pre-swizzled source, linear LDS dest)
    #pragma unroll
    for (int i = 0; i < 4; ++i) {
      int pos = ((i * 4 + w) << 10) + lane * 16;
      {
        int row = pos >> 8, csw = pos & 255;
        int csrc = csw ^ ((row & 7) << 4);
        gload16(k + (size_t)(bb * SEQ + kvt * 64 + row) * qk_stride + h * HD + (csrc >> 1),
                (char*)k_lds + ((i * 4 + w) << 10));
      }
      {
        int row = pos >> 7, csw = pos & 127;
        int csrc = csw ^ ((row & 7) << 4);
        gload16(vt + ((size_t)pr * HD + row) * SEQ + kvt * 64 + (csrc >> 1),
                (char*)vt_lds + ((i * 4 + w) << 10));
      }
    }
    __syncthreads();

    // ---- S = Q K^T
    f32x4 s[2][4] = {};
    #pragma unroll
    for (int kk = 0; kk < 4; ++kk) {
      short8 bk[4];
      #pragma unroll
      for (int nn = 0; nn < 4; ++nn) {
        int row = nn * 16 + l15;
        int col = kk * 64 + g * 16;
        bk[nn] = *(const short8*)((const char*)k_lds + row * 256 + (col ^ ((row & 7) << 4)));
      }
      #pragma unroll
      for (int mm = 0; mm < 2; ++mm)
        #pragma unroll
        for (int nn = 0; nn < 4; ++nn)
          s[mm][nn] = __builtin_amdgcn_mfma_f32_16x16x32_bf16(aq[mm][kk], bk[nn], s[mm][nn], 0, 0, 0);
    }

    // ---- mask + online softmax + P to LDS
    bool diag = (kvt >= 2 * qt);
    #pragma unroll
    for (int mm = 0; mm < 2; ++mm) {
      float mx[4] = {-1e30f, -1e30f, -1e30f, -1e30f};
      #pragma unroll
      for (int nn = 0; nn < 4; ++nn)
        #pragma unroll
        for (int r = 0; r < 4; ++r) {
          float sv = s[mm][nn][r] * SCL;
          if (diag) {
            int kvg = kvt * 64 + nn * 16 + l15;
            int qg = qrow_base + mm * 16 + g * 4 + r;
            if (kvg > qg) sv = -1e30f;
          }
          s[mm][nn][r] = sv;
          mx[r] = fmaxf(mx[r], sv);
        }
      #pragma unroll
      for (int r = 0; r < 4; ++r) {
        mx[r] = fmaxf(mx[r], __shfl_xor(mx[r], 1));
        mx[r] = fmaxf(mx[r], __shfl_xor(mx[r], 2));
        mx[r] = fmaxf(mx[r], __shfl_xor(mx[r], 4));
        mx[r] = fmaxf(mx[r], __shfl_xor(mx[r], 8));
        float mn = fmaxf(m2[mm][r], mx[r]);
        float al = exp2f(m2[mm][r] - mn);
        m2[mm][r] = mn;
        ls[mm][r] *= al;
        #pragma unroll
        for (int dd = 0; dd < 8; ++dd) o[mm][dd][r] *= al;
      }
      #pragma unroll
      for (int nn = 0; nn < 4; ++nn)
        #pragma unroll
        for (int r = 0; r < 4; ++r) {
          float pv = exp2f(s[mm][nn][r] - m2[mm][r]);
          ls[mm][r] += pv;
          int row = mm * 16 + g * 4 + r;
          int colb = (nn * 16 + l15) * 2;
          *(unsigned short*)((char*)p_lds[w] + row * 128 + (colb ^ (((row >> 1) & 7) << 4))) = f2b(pv);
        }
    }

    // ---- O += P V  (B operand from VT)
    #pragma unroll
    for (int kk = 0; kk < 2; ++kk) {
      short8 pf[2], vf[8];
      #pragma unroll
      for (int mm = 0; mm < 2; ++mm) {
        int row = mm * 16 + l15;
        int col = kk * 64 + g * 16;
        pf[mm] = *(const short8*)((const char*)p_lds[w] + row * 128 + (col ^ (((row >> 1) & 7) << 4)));
      }
      #pragma unroll
      for (int dd = 0; dd < 8; ++dd) {
        int row = dd * 16 + l15;
        int col = kk * 64 + g * 16;
        vf[dd] = *(const short8*)((const char*)vt_lds + row * 128 + (col ^ ((row & 7) << 4)));
      }
      #pragma unroll
      for (int mm = 0; mm < 2; ++mm)
        #pragma unroll
        for (int dd = 0; dd < 8; ++dd)
          o[mm][dd] = __builtin_amdgcn_mfma_f32_16x16x32_bf16(pf[mm], vf[dd], o[mm][dd], 0, 0, 0);
    }
    __syncthreads();
  }

  // ---- finalize
  #pragma unroll
  for (int mm = 0; mm < 2; ++mm) {
    float inv[4];
    #pragma unroll
    for (int r = 0; r < 4; ++r) {
      float tt = ls[mm][r];
      tt += __shfl_xor(tt, 1);
      tt += __shfl_xor(tt, 2);
      tt += __shfl_xor(tt, 4);
      tt += __shfl_xor(tt, 8);
      inv[r] = 1.f / tt;
    }
    #pragma unroll
    for (int dd = 0; dd < 8; ++dd)
      #pragma unroll
      for (int r = 0; r < 4; ++r) {
        size_t n = (size_t)(bb * SEQ + qrow_base + mm * 16 + g * 4 + r);
        int col = h * HD + dd * 16 + l15;
        ao[n * DM + col] = f2b(o[mm][dd][r] * inv[r]);
      }
  }
}

// ---------------------------------------------------------------- launch
extern "C" void kernel_launch(void* const* d_in, const int* in_sizes, int n_in,
                              void* d_out, int out_size, void* d_ws, size_t ws_size,
                              hipStream_t stream) {
  const int* tokens = (const int*)d_in[0];
  const float* tok_emb = (const float*)d_in[1];
  const float* wq = (const float*)d_in[2];
  const float* wk = (const float*)d_in[3];
  const float* wv = (const float*)d_in[4];
  const float* wo = (const float*)d_in[5];
  const float* attn_nw = (const float*)d_in[6];
  const float* ffn_nw = (const float*)d_in[7];
  const float* final_nw = (const float*)d_in[8];
  const float* w1 = (const float*)d_in[9];
  const float* w2 = (const float*)d_in[10];
  const float* out_proj = (const float*)d_in[11];
  float* out = (float*)d_out;

  char* ws = (char*)d_ws;
  size_t off = 0;
  auto alloc = [&](size_t bytes) -> char* {
    char* p = ws + off;
    off += (bytes + 255) & ~(size_t)255;
    return p;
  };
  unsigned short* wqkv_b = (unsigned short*)alloc((size_t)3 * DM * DM * 2);
  unsigned short* wo_b = (unsigned short*)alloc((size_t)DM * DM * 2);
  unsigned short* w1_b = (unsigned short*)alloc((size_t)DFF * DM * 2);
  unsigned short* w2_b = (unsigned short*)alloc((size_t)DM * DFF * 2);
  unsigned short* wop_b = (unsigned short*)alloc((size_t)NVOCAB * DM * 2);
  float* x = (float*)alloc((size_t)NTOK * DM * 4);
  unsigned short* xn = (unsigned short*)alloc((size_t)NTOK * DM * 2);
  unsigned short* qkv_b = (unsigned short*)alloc((size_t)NTOK * 3 * DM * 2);
  unsigned short* vt_b = (unsigned short*)alloc((size_t)NTOK * DM * 2);
  unsigned short* ao_b = (unsigned short*)alloc((size_t)NTOK * DM * 2);
  unsigned short* h1_b = qkv_b;  // alias: qkv(50MB)+vt(17MB) dead when h1 written

  auto conv = [&](const float* src, unsigned short* dst, size_t n) {
    int nq = (int)(n / 4);
    int grid = (nq + 255) / 256;
    if (grid > 4096) grid = 4096;
    k_f32_to_bf16<<<grid, 256, 0, stream>>>(src, dst, nq);
  };
  conv(wq, wqkv_b, (size_t)DM * DM);
  conv(wk, wqkv_b + (size_t)DM * DM, (size_t)DM * DM);
  conv(wv, wqkv_b + (size_t)2 * DM * DM, (size_t)DM * DM);
  conv(wo, wo_b, (size_t)DM * DM);
  conv(w1, w1_b, (size_t)DFF * DM);
  conv(w2, w2_b, (size_t)DM * DFF);
  conv(out_proj, wop_b, (size_t)NVOCAB * DM);

  k_embed<<<NTOK, 256, 0, stream>>>(tokens, tok_emb, x);
  k_rmsnorm<<<NTOK, 256, 0, stream>>>(x, attn_nw, xn);

  // fused QKV: [4096, 6144]
  k_gemm_nt<EPI_BF16><<<(NTOK / 128) * (3 * DM / 128), 256, 0, stream>>>(
      xn, wqkv_b, NTOK, 3 * DM, DM, nullptr, qkv_b, nullptr);

  k_transpose_v<<<32 * 32, 256, 0, stream>>>(qkv_b + 2 * DM, 3 * DM, vt_b);
  k_attn<<<32 * 16, 256, 0, stream>>>(qkv_b, qkv_b + DM, vt_b, ao_b, 3 * DM);

  k_gemm_nt<EPI_RESID><<<(NTOK / 128) * (DM / 128), 256, 0, stream>>>(
      ao_b, wo_b, NTOK, DM, DM, x, nullptr, x);

  k_rmsnorm<<<NTOK, 256, 0, stream>>>(x, ffn_nw, xn);
  k_gemm_nt<EPI_SILU><<<(NTOK / 128) * (DFF / 128), 256, 0, stream>>>(
      xn, w1_b, NTOK, DFF, DM, nullptr, h1_b, nullptr);
  k_gemm_nt<EPI_RESID><<<(NTOK / 128) * (DM / 128), 256, 0, stream>>>(
      h1_b, w2_b, NTOK, DM, DFF, x, nullptr, x);

  k_rmsnorm<<<NTOK, 256, 0, stream>>>(x, final_nw, xn);
  k_gemm_nt<EPI_F32><<<(NTOK / 128) * (NVOCAB / 128), 256, 0, stream>>>(
      xn, wop_b, NTOK, NVOCAB, DM, out, nullptr, nullptr);
}

// Round 3
// 1469.927 us; speedup vs baseline: 1.2468x; 1.2468x over previous
//
#include <hip/hip_runtime.h>
#include <stdint.h>

#define DM     2048
#define NHE    16
#define DFF    8192
#define NBATCH 2
#define SEQ    2048
#define NTOK   4096
#define HD     128
#define NVOCAB 32000

typedef __attribute__((ext_vector_type(8))) short short8;
typedef __attribute__((ext_vector_type(4))) float f32x4;
typedef __attribute__((ext_vector_type(4))) unsigned short u16x4;

static __device__ __forceinline__ unsigned short f2b(float f) {
  union { float f; uint32_t u; } v; v.f = f;
  return (unsigned short)((v.u + 0x7FFFu + ((v.u >> 16) & 1u)) >> 16);
}

static __device__ __forceinline__ void gload16(const void* g, void* l) {
  __builtin_amdgcn_global_load_lds(
      (const __attribute__((address_space(1))) unsigned int*)g,
      (__attribute__((address_space(3))) unsigned int*)l, 16, 0, 0);
}

// ---------------------------------------------------------------- conversions
__global__ void k_f32_to_bf16(const float* __restrict__ in,
                              unsigned short* __restrict__ out, int nq) {
  int i = blockIdx.x * blockDim.x + threadIdx.x;
  int stride = gridDim.x * blockDim.x;
  for (; i < nq; i += stride) {
    float4 v = ((const float4*)in)[i];
    u16x4 o;
    o.x = f2b(v.x); o.y = f2b(v.y); o.z = f2b(v.z); o.w = f2b(v.w);
    ((u16x4*)out)[i] = o;
  }
}

// ---------------------------------------------------------------- embedding
__global__ void k_embed(const int* __restrict__ tok,
                        const float* __restrict__ emb, float* __restrict__ x) {
  int n = blockIdx.x;
  int t = tok[n];
  const float4* src = (const float4*)(emb + (size_t)t * DM);
  float4* dst = (float4*)(x + (size_t)n * DM);
  for (int i = threadIdx.x; i < DM / 4; i += blockDim.x) dst[i] = src[i];
}

// ---------------------------------------------------------------- rmsnorm
__global__ void k_rmsnorm(const float* __restrict__ x, const float* __restrict__ wt,
                          unsigned short* __restrict__ out) {
  int n = blockIdx.x;
  const float* row = x + (size_t)n * DM;
  float ss = 0.f;
  #pragma unroll
  for (int it = 0; it < 2; ++it) {
    int i = threadIdx.x * 4 + it * 1024;
    float4 v = *(const float4*)(row + i);
    ss += v.x * v.x + v.y * v.y + v.z * v.z + v.w * v.w;
  }
  #pragma unroll
  for (int m = 1; m < 64; m <<= 1) ss += __shfl_xor(ss, m);
  __shared__ float p[4];
  if ((threadIdx.x & 63) == 0) p[threadIdx.x >> 6] = ss;
  __syncthreads();
  float inv = rsqrtf((p[0] + p[1] + p[2] + p[3]) * (1.f / DM) + 1e-6f);
  #pragma unroll
  for (int it = 0; it < 2; ++it) {
    int i = threadIdx.x * 4 + it * 1024;
    float4 v = *(const float4*)(row + i);
    float4 w4 = *(const float4*)(wt + i);
    u16x4 o;
    o.x = f2b(v.x * w4.x * inv); o.y = f2b(v.y * w4.y * inv);
    o.z = f2b(v.z * w4.z * inv); o.w = f2b(v.w * w4.w * inv);
    *(u16x4*)(out + (size_t)n * DM + i) = o;
  }
}

// ---------------------------------------------------------------- GEMM (NT)
// C[M,N] = A[M,K] * B[N,K]^T ; bf16 in, f32 accum.
// 256x128 tile, BK=64, 8 waves (4Mx2N), triple-buffered LDS (144KB),
// counted-vmcnt software pipeline: STAGE(kt+2); vmcnt(12); bar; compute; bar.
#define EPI_BF16  0
#define EPI_RESID 1
#define EPI_SILU  2
#define EPI_F32   3

template <int EPI>
__launch_bounds__(512, 2)
__global__ void k_gemm_nt(const unsigned short* __restrict__ A,
                          const unsigned short* __restrict__ Bm,
                          int M, int N, int K,
                          float* __restrict__ Cf, unsigned short* __restrict__ Cb,
                          const float* __restrict__ R) {
  // per buffer: A tile 256x64 (32KB = 16384 ush), B tile 128x64 (16KB = 8192 ush)
  __shared__ unsigned short lds[3 * 24576];
  int nbn = N >> 7;
  int nwg = gridDim.x;
  int bid = blockIdx.x;
  int cpx = nwg >> 3;                       // all grids are multiples of 8
  bid = (bid & 7) * cpx + (bid >> 3);       // XCD-bijective swizzle
  int bm = bid / nbn, bn = bid % nbn;       // bm-major (round-1 proven)
  int t = threadIdx.x, w = t >> 6, lane = t & 63;
  int wr = w >> 1, wc = w & 1;              // 4 (M) x 2 (N) waves
  int g = lane >> 4, l15 = lane & 15;

  f32x4 acc[4][4] = {};

  size_t abase = (size_t)(bm * 256) * K;
  size_t bbase = (size_t)(bn * 128) * K;
  int nkt = K >> 6;

  auto stage = [&](int buf, int kt) {
    unsigned short* dst = lds + buf * 24576;
    int k0 = kt << 6;
    #pragma unroll
    for (int i = 0; i < 4; ++i) {
      int pos = (i * 512 + t) << 4;          // byte pos in 32KB A region
      int row = pos >> 7, colb = pos & 127;
      int csrc = colb ^ ((row & 7) << 4);
      gload16(A + abase + (size_t)row * K + k0 + (csrc >> 1), (char*)dst + pos);
    }
    #pragma unroll
    for (int i = 0; i < 2; ++i) {
      int pos = (i * 512 + t) << 4;          // byte pos in 16KB B region
      int row = pos >> 7, colb = pos & 127;
      int csrc = colb ^ ((row & 7) << 4);
      gload16(Bm + bbase + (size_t)row * K + k0 + (csrc >> 1),
              (char*)(dst + 16384) + pos);
    }
  };

  stage(0, 0);
  if (nkt > 1) stage(1, 1);

  int rb = 0, sb = 2;
  for (int kt = 0; kt < nkt; ++kt) {
    if (kt + 2 < nkt) {
      stage(sb, kt + 2);
      asm volatile("s_waitcnt vmcnt(12)" ::: "memory");
    } else if (kt + 1 < nkt) {
      asm volatile("s_waitcnt vmcnt(6)" ::: "memory");
    } else {
      asm volatile("s_waitcnt vmcnt(0)" ::: "memory");
    }
    __builtin_amdgcn_s_barrier();
    __builtin_amdgcn_sched_barrier(0);

    const unsigned short* abuf = lds + rb * 24576;
    const unsigned short* bbuf = abuf + 16384;
    __builtin_amdgcn_s_setprio(1);
    #pragma unroll
    for (int kk = 0; kk < 2; ++kk) {
      short8 af[4], bfr[4];
      #pragma unroll
      for (int mm = 0; mm < 4; ++mm) {
        int row = wr * 64 + mm * 16 + l15;
        int col = kk * 64 + g * 16;
        af[mm] = *(const short8*)((const char*)abuf + row * 128 + (col ^ ((row & 7) << 4)));
      }
      #pragma unroll
      for (int nn = 0; nn < 4; ++nn) {
        int row = wc * 64 + nn * 16 + l15;
        int col = kk * 64 + g * 16;
        bfr[nn] = *(const short8*)((const char*)bbuf + row * 128 + (col ^ ((row & 7) << 4)));
      }
      #pragma unroll
      for (int mm = 0; mm < 4; ++mm)
        #pragma unroll
        for (int nn = 0; nn < 4; ++nn)
          acc[mm][nn] = __builtin_amdgcn_mfma_f32_16x16x32_bf16(af[mm], bfr[nn], acc[mm][nn], 0, 0, 0);
    }
    __builtin_amdgcn_s_setprio(0);
    __builtin_amdgcn_sched_barrier(0);
    __builtin_amdgcn_s_barrier();

    rb = (rb == 2) ? 0 : rb + 1;
    sb = (sb == 2) ? 0 : sb + 1;
  }

  #pragma unroll
  for (int mm = 0; mm < 4; ++mm) {
    #pragma unroll
    for (int nn = 0; nn < 4; ++nn) {
      #pragma unroll
      for (int r = 0; r < 4; ++r) {
        int grow = bm * 256 + wr * 64 + mm * 16 + g * 4 + r;
        int gcol = bn * 128 + wc * 64 + nn * 16 + l15;
        size_t off = (size_t)grow * N + gcol;
        float v = acc[mm][nn][r];
        if (EPI == EPI_BF16) {
          Cb[off] = f2b(v);
        } else if (EPI == EPI_RESID) {
          Cf[off] = R[off] + v;
        } else if (EPI == EPI_SILU) {
          float s = 1.f / (1.f + __expf(-v));
          Cb[off] = f2b(v * s);
        } else {
          Cf[off] = v;
        }
      }
    }
  }
}

// ---------------------------------------------------------------- V transpose
__global__ void k_transpose_v(const unsigned short* __restrict__ v, int vstride,
                              unsigned short* __restrict__ vt) {
  __shared__ unsigned short tile[64][136];
  int pr = blockIdx.x >> 5;     // pair
  int st = blockIdx.x & 31;     // s-tile of 64
  int bb = pr >> 4, h = pr & 15;
  int row = threadIdx.x >> 2;
  int cq = threadIdx.x & 3;
  const unsigned short* src =
      v + (size_t)(bb * SEQ + st * 64 + row) * vstride + h * HD + cq * 32;
  #pragma unroll
  for (int j = 0; j < 4; ++j)
    *(short8*)&tile[row][cq * 32 + j * 8] = *(const short8*)(src + j * 8);
  __syncthreads();
  int d = threadIdx.x >> 1;
  int sh = threadIdx.x & 1;
  unsigned short tmp[32];
  #pragma unroll
  for (int j = 0; j < 32; ++j) tmp[j] = tile[sh * 32 + j][d];
  unsigned short* dst = vt + ((size_t)pr * HD + d) * SEQ + st * 64 + sh * 32;
  #pragma unroll
  for (int j = 0; j < 4; ++j)
    *(short8*)(dst + j * 8) = *(const short8*)&tmp[j * 8];
}

// ---------------------------------------------------------------- attention
__launch_bounds__(256)
__global__ void k_attn(const unsigned short* __restrict__ q,
                       const unsigned short* __restrict__ k,
                       const unsigned short* __restrict__ vt,
                       unsigned short* __restrict__ ao, int qk_stride) {
  __shared__ unsigned short k_lds[64 * 128];
  __shared__ unsigned short vt_lds[128 * 64];
  __shared__ unsigned short p_lds[4][32 * 64];

  int bid = blockIdx.x;
  int pr = bid >> 4;
  int qt = 15 - (bid & 15);
  int bb = pr >> 4, h = pr & 15;
  int t = threadIdx.x, w = t >> 6, lane = t & 63;
  int g = lane >> 4, l15 = lane & 15;
  const float SCL = 0.08838834764831845f * 1.4426950408889634f;

  int qrow_base = qt * 128 + w * 32;
  short8 aq[2][4];
  #pragma unroll
  for (int mm = 0; mm < 2; ++mm) {
    size_t n = (size_t)(bb * SEQ + qrow_base + mm * 16 + l15);
    #pragma unroll
    for (int kk = 0; kk < 4; ++kk)
      aq[mm][kk] = *(const short8*)(q + n * qk_stride + h * HD + kk * 32 + g * 8);
  }

  f32x4 o[2][8] = {};
  float m2[2][4], ls[2][4];
  #pragma unroll
  for (int mm = 0; mm < 2; ++mm)
    #pragma unroll
    for (int r = 0; r < 4; ++r) { m2[mm][r] = -1e30f; ls[mm][r] = 0.f; }

  int nkv = 2 * qt + 2;
  for (int kvt = 0; kvt < nkv; ++kvt) {
    #pragma unroll
    for (int i = 0; i < 4; ++i) {
      int pos = ((i * 4 + w) << 10) + lane * 16;
      {
        int row = pos >> 8, csw = pos & 255;
        int csrc = csw ^ ((row & 7) << 4);
        gload16(k + (size_t)(bb * SEQ + kvt * 64 + row) * qk_stride + h * HD + (csrc >> 1),
                (char*)k_lds + ((i * 4 + w) << 10));
      }
      {
        int row = pos >> 7, csw = pos & 127;
        int csrc = csw ^ ((row & 7) << 4);
        gload16(vt + ((size_t)pr * HD + row) * SEQ + kvt * 64 + (csrc >> 1),
                (char*)vt_lds + ((i * 4 + w) << 10));
      }
    }
    __syncthreads();

    f32x4 s[2][4] = {};
    #pragma unroll
    for (int kk = 0; kk < 4; ++kk) {
      short8 bk[4];
      #pragma unroll
      for (int nn = 0; nn < 4; ++nn) {
        int row = nn * 16 + l15;
        int col = kk * 64 + g * 16;
        bk[nn] = *(const short8*)((const char*)k_lds + row * 256 + (col ^ ((row & 7) << 4)));
      }
      #pragma unroll
      for (int mm = 0; mm < 2; ++mm)
        #pragma unroll
        for (int nn = 0; nn < 4; ++nn)
          s[mm][nn] = __builtin_amdgcn_mfma_f32_16x16x32_bf16(aq[mm][kk], bk[nn], s[mm][nn], 0, 0, 0);
    }

    bool diag = (kvt >= 2 * qt);
    #pragma unroll
    for (int mm = 0; mm < 2; ++mm) {
      float mx[4] = {-1e30f, -1e30f, -1e30f, -1e30f};
      #pragma unroll
      for (int nn = 0; nn < 4; ++nn)
        #pragma unroll
        for (int r = 0; r < 4; ++r) {
          float sv = s[mm][nn][r] * SCL;
          if (diag) {
            int kvg = kvt * 64 + nn * 16 + l15;
            int qg = qrow_base + mm * 16 + g * 4 + r;
            if (kvg > qg) sv = -1e30f;
          }
          s[mm][nn][r] = sv;
          mx[r] = fmaxf(mx[r], sv);
        }
      #pragma unroll
      for (int r = 0; r < 4; ++r) {
        mx[r] = fmaxf(mx[r], __shfl_xor(mx[r], 1));
        mx[r] = fmaxf(mx[r], __shfl_xor(mx[r], 2));
        mx[r] = fmaxf(mx[r], __shfl_xor(mx[r], 4));
        mx[r] = fmaxf(mx[r], __shfl_xor(mx[r], 8));
        float mn = fmaxf(m2[mm][r], mx[r]);
        float al = exp2f(m2[mm][r] - mn);
        m2[mm][r] = mn;
        ls[mm][r] *= al;
        #pragma unroll
        for (int dd = 0; dd < 8; ++dd) o[mm][dd][r] *= al;
      }
      #pragma unroll
      for (int nn = 0; nn < 4; ++nn)
        #pragma unroll
        for (int r = 0; r < 4; ++r) {
          float pv = exp2f(s[mm][nn][r] - m2[mm][r]);
          ls[mm][r] += pv;
          int row = mm * 16 + g * 4 + r;
          int colb = (nn * 16 + l15) * 2;
          *(unsigned short*)((char*)p_lds[w] + row * 128 + (colb ^ (((row >> 1) & 7) << 4))) = f2b(pv);
        }
    }

    #pragma unroll
    for (int kk = 0; kk < 2; ++kk) {
      short8 pf[2], vf[8];
      #pragma unroll
      for (int mm = 0; mm < 2; ++mm) {
        int row = mm * 16 + l15;
        int col = kk * 64 + g * 16;
        pf[mm] = *(const short8*)((const char*)p_lds[w] + row * 128 + (col ^ (((row >> 1) & 7) << 4)));
      }
      #pragma unroll
      for (int dd = 0; dd < 8; ++dd) {
        int row = dd * 16 + l15;
        int col = kk * 64 + g * 16;
        vf[dd] = *(const short8*)((const char*)vt_lds + row * 128 + (col ^ ((row & 7) << 4)));
      }
      #pragma unroll
      for (int mm = 0; mm < 2; ++mm)
        #pragma unroll
        for (int dd = 0; dd < 8; ++dd)
          o[mm][dd] = __builtin_amdgcn_mfma_f32_16x16x32_bf16(pf[mm], vf[dd], o[mm][dd], 0, 0, 0);
    }
    __syncthreads();
  }

  #pragma unroll
  for (int mm = 0; mm < 2; ++mm) {
    float inv[4];
    #pragma unroll
    for (int r = 0; r < 4; ++r) {
      float tt = ls[mm][r];
      tt += __shfl_xor(tt, 1);
      tt += __shfl_xor(tt, 2);
      tt += __shfl_xor(tt, 4);
      tt += __shfl_xor(tt, 8);
      inv[r] = 1.f / tt;
    }
    #pragma unroll
    for (int dd = 0; dd < 8; ++dd)
      #pragma unroll
      for (int r = 0; r < 4; ++r) {
        size_t n = (size_t)(bb * SEQ + qrow_base + mm * 16 + g * 4 + r);
        int col = h * HD + dd * 16 + l15;
        ao[n * DM + col] = f2b(o[mm][dd][r] * inv[r]);
      }
  }
}

// ---------------------------------------------------------------- launch
extern "C" void kernel_launch(void* const* d_in, const int* in_sizes, int n_in,
                              void* d_out, int out_size, void* d_ws, size_t ws_size,
                              hipStream_t stream) {
  const int* tokens = (const int*)d_in[0];
  const float* tok_emb = (const float*)d_in[1];
  const float* wq = (const float*)d_in[2];
  const float* wk = (const float*)d_in[3];
  const float* wv = (const float*)d_in[4];
  const float* wo = (const float*)d_in[5];
  const float* attn_nw = (const float*)d_in[6];
  const float* ffn_nw = (const float*)d_in[7];
  const float* final_nw = (const float*)d_in[8];
  const float* w1 = (const float*)d_in[9];
  const float* w2 = (const float*)d_in[10];
  const float* out_proj = (const float*)d_in[11];
  float* out = (float*)d_out;

  char* ws = (char*)d_ws;
  size_t off = 0;
  auto alloc = [&](size_t bytes) -> char* {
    char* p = ws + off;
    off += (bytes + 255) & ~(size_t)255;
    return p;
  };
  unsigned short* wqkv_b = (unsigned short*)alloc((size_t)3 * DM * DM * 2);
  unsigned short* wo_b = (unsigned short*)alloc((size_t)DM * DM * 2);
  unsigned short* w1_b = (unsigned short*)alloc((size_t)DFF * DM * 2);
  unsigned short* w2_b = (unsigned short*)alloc((size_t)DM * DFF * 2);
  unsigned short* wop_b = (unsigned short*)alloc((size_t)NVOCAB * DM * 2);
  float* x = (float*)alloc((size_t)NTOK * DM * 4);
  unsigned short* xn = (unsigned short*)alloc((size_t)NTOK * DM * 2);
  unsigned short* qkv_b = (unsigned short*)alloc((size_t)NTOK * 3 * DM * 2);
  unsigned short* vt_b = (unsigned short*)alloc((size_t)NTOK * DM * 2);
  unsigned short* ao_b = (unsigned short*)alloc((size_t)NTOK * DM * 2);
  unsigned short* h1_b = qkv_b;  // alias: qkv+vt dead when h1 written

  auto conv = [&](const float* src, unsigned short* dst, size_t n) {
    int nq = (int)(n / 4);
    int grid = (nq + 255) / 256;
    if (grid > 4096) grid = 4096;
    k_f32_to_bf16<<<grid, 256, 0, stream>>>(src, dst, nq);
  };
  conv(wq, wqkv_b, (size_t)DM * DM);
  conv(wk, wqkv_b + (size_t)DM * DM, (size_t)DM * DM);
  conv(wv, wqkv_b + (size_t)2 * DM * DM, (size_t)DM * DM);
  conv(wo, wo_b, (size_t)DM * DM);
  conv(w1, w1_b, (size_t)DFF * DM);
  conv(w2, w2_b, (size_t)DM * DFF);
  conv(out_proj, wop_b, (size_t)NVOCAB * DM);

  k_embed<<<NTOK, 256, 0, stream>>>(tokens, tok_emb, x);
  k_rmsnorm<<<NTOK, 256, 0, stream>>>(x, attn_nw, xn);

  // fused QKV: [4096, 6144]
  k_gemm_nt<EPI_BF16><<<(NTOK / 256) * (3 * DM / 128), 512, 0, stream>>>(
      xn, wqkv_b, NTOK, 3 * DM, DM, nullptr, qkv_b, nullptr);

  k_transpose_v<<<32 * 32, 256, 0, stream>>>(qkv_b + 2 * DM, 3 * DM, vt_b);
  k_attn<<<32 * 16, 256, 0, stream>>>(qkv_b, qkv_b + DM, vt_b, ao_b, 3 * DM);

  k_gemm_nt<EPI_RESID><<<(NTOK / 256) * (DM / 128), 512, 0, stream>>>(
      ao_b, wo_b, NTOK, DM, DM, x, nullptr, x);

  k_rmsnorm<<<NTOK, 256, 0, stream>>>(x, ffn_nw, xn);
  k_gemm_nt<EPI_SILU><<<(NTOK / 256) * (DFF / 128), 512, 0, stream>>>(
      xn, w1_b, NTOK, DFF, DM, nullptr, h1_b, nullptr);
  k_gemm_nt<EPI_RESID><<<(NTOK / 256) * (DM / 128), 512, 0, stream>>>(
      h1_b, w2_b, NTOK, DM, DFF, x, nullptr, x);

  k_rmsnorm<<<NTOK, 256, 0, stream>>>(x, final_nw, xn);
  k_gemm_nt<EPI_F32><<<(NTOK / 256) * (NVOCAB / 128), 512, 0, stream>>>(
      xn, wop_b, NTOK, NVOCAB, DM, out, nullptr, nullptr);
}

// Round 4
// 1458.276 us; speedup vs baseline: 1.2568x; 1.0080x over previous
//
#include <hip/hip_runtime.h>
#include <stdint.h>

#define DM     2048
#define NHE    16
#define DFF    8192
#define NBATCH 2
#define SEQ    2048
#define NTOK   4096
#define HD     128
#define NVOCAB 32000

typedef __attribute__((ext_vector_type(8))) short short8;
typedef __attribute__((ext_vector_type(4))) float f32x4;
typedef __attribute__((ext_vector_type(4))) unsigned short u16x4;

static __device__ __forceinline__ unsigned short f2b(float f) {
  union { float f; uint32_t u; } v; v.f = f;
  return (unsigned short)((v.u + 0x7FFFu + ((v.u >> 16) & 1u)) >> 16);
}

static __device__ __forceinline__ void gload16(const void* g, void* l) {
  __builtin_amdgcn_global_load_lds(
      (const __attribute__((address_space(1))) unsigned int*)g,
      (__attribute__((address_space(3))) unsigned int*)l, 16, 0, 0);
}

// ---------------------------------------------------------------- conversions
__global__ void k_f32_to_bf16(const float* __restrict__ in,
                              unsigned short* __restrict__ out, int nq) {
  int i = blockIdx.x * blockDim.x + threadIdx.x;
  int stride = gridDim.x * blockDim.x;
  for (; i < nq; i += stride) {
    float4 v = ((const float4*)in)[i];
    u16x4 o;
    o.x = f2b(v.x); o.y = f2b(v.y); o.z = f2b(v.z); o.w = f2b(v.w);
    ((u16x4*)out)[i] = o;
  }
}

// ---------------------------------------------------------------- embedding
__global__ void k_embed(const int* __restrict__ tok,
                        const float* __restrict__ emb, float* __restrict__ x) {
  int n = blockIdx.x;
  int t = tok[n];
  const float4* src = (const float4*)(emb + (size_t)t * DM);
  float4* dst = (float4*)(x + (size_t)n * DM);
  for (int i = threadIdx.x; i < DM / 4; i += blockDim.x) dst[i] = src[i];
}

// ---------------------------------------------------------------- rmsnorm
__global__ void k_rmsnorm(const float* __restrict__ x, const float* __restrict__ wt,
                          unsigned short* __restrict__ out) {
  int n = blockIdx.x;
  const float* row = x + (size_t)n * DM;
  float ss = 0.f;
  #pragma unroll
  for (int it = 0; it < 2; ++it) {
    int i = threadIdx.x * 4 + it * 1024;
    float4 v = *(const float4*)(row + i);
    ss += v.x * v.x + v.y * v.y + v.z * v.z + v.w * v.w;
  }
  #pragma unroll
  for (int m = 1; m < 64; m <<= 1) ss += __shfl_xor(ss, m);
  __shared__ float p[4];
  if ((threadIdx.x & 63) == 0) p[threadIdx.x >> 6] = ss;
  __syncthreads();
  float inv = rsqrtf((p[0] + p[1] + p[2] + p[3]) * (1.f / DM) + 1e-6f);
  #pragma unroll
  for (int it = 0; it < 2; ++it) {
    int i = threadIdx.x * 4 + it * 1024;
    float4 v = *(const float4*)(row + i);
    float4 w4 = *(const float4*)(wt + i);
    u16x4 o;
    o.x = f2b(v.x * w4.x * inv); o.y = f2b(v.y * w4.y * inv);
    o.z = f2b(v.z * w4.z * inv); o.w = f2b(v.w * w4.w * inv);
    *(u16x4*)(out + (size_t)n * DM + i) = o;
  }
}

// ---------------------------------------------------------------- GEMM (NT)
// C[M,N] = A[M,K] * B[N,K]^T ; bf16 in, f32 accum.
// 256x256 tile, BK=64, 8 waves (2Mx4N), per-wave 128x64 out (acc[8][4]).
// Double-buffered LDS (128KB), counted-vmcnt pipeline (round-3 skeleton):
//   stage(kt+1) -> vmcnt(8) -> bar -> setprio+compute -> bar.
#define EPI_BF16  0
#define EPI_RESID 1
#define EPI_SILU  2
#define EPI_F32   3

template <int EPI>
__launch_bounds__(512, 2)
__global__ void k_gemm_nt(const unsigned short* __restrict__ A,
                          const unsigned short* __restrict__ Bm,
                          int M, int N, int K,
                          float* __restrict__ Cf, unsigned short* __restrict__ Cb,
                          const float* __restrict__ R) {
  // per buffer: A tile 256x64 (32KB = 16384 ush) + B tile 256x64 (32KB)
  __shared__ unsigned short lds[2][32768];
  int nbn = N >> 8;
  int nwg = gridDim.x;
  int bid = blockIdx.x;
  int cpx = nwg >> 3;                       // all grids are multiples of 8
  bid = (bid & 7) * cpx + (bid >> 3);       // XCD-bijective swizzle
  int bm = bid / nbn, bn = bid % nbn;       // bm-major (round-1 proven)
  int t = threadIdx.x, w = t >> 6, lane = t & 63;
  int wr = w >> 2, wc = w & 3;              // 2 (M) x 4 (N) waves
  int g = lane >> 4, l15 = lane & 15;

  f32x4 acc[8][4] = {};

  size_t abase = (size_t)(bm * 256) * K;
  size_t bbase = (size_t)(bn * 256) * K;
  int nkt = K >> 6;

  auto stage = [&](int buf, int kt) {
    unsigned short* dst = lds[buf];
    int k0 = kt << 6;
    #pragma unroll
    for (int i = 0; i < 4; ++i) {
      int pos = (i * 512 + t) << 4;          // byte pos in 32KB A region
      int row = pos >> 7, colb = pos & 127;
      int csrc = colb ^ ((row & 7) << 4);
      gload16(A + abase + (size_t)row * K + k0 + (csrc >> 1), (char*)dst + pos);
    }
    #pragma unroll
    for (int i = 0; i < 4; ++i) {
      int pos = (i * 512 + t) << 4;          // byte pos in 32KB B region
      int row = pos >> 7, colb = pos & 127;
      int csrc = colb ^ ((row & 7) << 4);
      gload16(Bm + bbase + (size_t)row * K + k0 + (csrc >> 1),
              (char*)(dst + 16384) + pos);
    }
  };

  stage(0, 0);
  for (int kt = 0; kt < nkt; ++kt) {
    int cur = kt & 1;
    if (kt + 1 < nkt) {
      stage(1 - cur, kt + 1);
      asm volatile("s_waitcnt vmcnt(8)" ::: "memory");
    } else {
      asm volatile("s_waitcnt vmcnt(0)" ::: "memory");
    }
    __builtin_amdgcn_s_barrier();
    __builtin_amdgcn_sched_barrier(0);

    const unsigned short* abuf = lds[cur];
    const unsigned short* bbuf = abuf + 16384;
    __builtin_amdgcn_s_setprio(1);
    #pragma unroll
    for (int kk = 0; kk < 2; ++kk) {
      short8 af[8], bfr[4];
      #pragma unroll
      for (int mm = 0; mm < 8; ++mm) {
        int row = wr * 128 + mm * 16 + l15;
        int col = kk * 64 + g * 16;
        af[mm] = *(const short8*)((const char*)abuf + row * 128 + (col ^ ((row & 7) << 4)));
      }
      #pragma unroll
      for (int nn = 0; nn < 4; ++nn) {
        int row = wc * 64 + nn * 16 + l15;
        int col = kk * 64 + g * 16;
        bfr[nn] = *(const short8*)((const char*)bbuf + row * 128 + (col ^ ((row & 7) << 4)));
      }
      #pragma unroll
      for (int mm = 0; mm < 8; ++mm)
        #pragma unroll
        for (int nn = 0; nn < 4; ++nn)
          acc[mm][nn] = __builtin_amdgcn_mfma_f32_16x16x32_bf16(af[mm], bfr[nn], acc[mm][nn], 0, 0, 0);
    }
    __builtin_amdgcn_s_setprio(0);
    __builtin_amdgcn_sched_barrier(0);
    __builtin_amdgcn_s_barrier();
  }

  #pragma unroll
  for (int mm = 0; mm < 8; ++mm) {
    #pragma unroll
    for (int nn = 0; nn < 4; ++nn) {
      #pragma unroll
      for (int r = 0; r < 4; ++r) {
        int grow = bm * 256 + wr * 128 + mm * 16 + g * 4 + r;
        int gcol = bn * 256 + wc * 64 + nn * 16 + l15;
        size_t off = (size_t)grow * N + gcol;
        float v = acc[mm][nn][r];
        if (EPI == EPI_BF16) {
          Cb[off] = f2b(v);
        } else if (EPI == EPI_RESID) {
          Cf[off] = R[off] + v;
        } else if (EPI == EPI_SILU) {
          float s = 1.f / (1.f + __expf(-v));
          Cb[off] = f2b(v * s);
        } else {
          Cf[off] = v;
        }
      }
    }
  }
}

// ---------------------------------------------------------------- V transpose
__global__ void k_transpose_v(const unsigned short* __restrict__ v, int vstride,
                              unsigned short* __restrict__ vt) {
  __shared__ unsigned short tile[64][136];
  int pr = blockIdx.x >> 5;     // pair
  int st = blockIdx.x & 31;     // s-tile of 64
  int bb = pr >> 4, h = pr & 15;
  int row = threadIdx.x >> 2;
  int cq = threadIdx.x & 3;
  const unsigned short* src =
      v + (size_t)(bb * SEQ + st * 64 + row) * vstride + h * HD + cq * 32;
  #pragma unroll
  for (int j = 0; j < 4; ++j)
    *(short8*)&tile[row][cq * 32 + j * 8] = *(const short8*)(src + j * 8);
  __syncthreads();
  int d = threadIdx.x >> 1;
  int sh = threadIdx.x & 1;
  unsigned short tmp[32];
  #pragma unroll
  for (int j = 0; j < 32; ++j) tmp[j] = tile[sh * 32 + j][d];
  unsigned short* dst = vt + ((size_t)pr * HD + d) * SEQ + st * 64 + sh * 32;
  #pragma unroll
  for (int j = 0; j < 4; ++j)
    *(short8*)(dst + j * 8) = *(const short8*)&tmp[j * 8];
}

// ---------------------------------------------------------------- attention
__launch_bounds__(256)
__global__ void k_attn(const unsigned short* __restrict__ q,
                       const unsigned short* __restrict__ k,
                       const unsigned short* __restrict__ vt,
                       unsigned short* __restrict__ ao, int qk_stride) {
  __shared__ unsigned short k_lds[64 * 128];
  __shared__ unsigned short vt_lds[128 * 64];
  __shared__ unsigned short p_lds[4][32 * 64];

  int bid = blockIdx.x;
  int pr = bid >> 4;
  int qt = 15 - (bid & 15);
  int bb = pr >> 4, h = pr & 15;
  int t = threadIdx.x, w = t >> 6, lane = t & 63;
  int g = lane >> 4, l15 = lane & 15;
  const float SCL = 0.08838834764831845f * 1.4426950408889634f;

  int qrow_base = qt * 128 + w * 32;
  short8 aq[2][4];
  #pragma unroll
  for (int mm = 0; mm < 2; ++mm) {
    size_t n = (size_t)(bb * SEQ + qrow_base + mm * 16 + l15);
    #pragma unroll
    for (int kk = 0; kk < 4; ++kk)
      aq[mm][kk] = *(const short8*)(q + n * qk_stride + h * HD + kk * 32 + g * 8);
  }

  f32x4 o[2][8] = {};
  float m2[2][4], ls[2][4];
  #pragma unroll
  for (int mm = 0; mm < 2; ++mm)
    #pragma unroll
    for (int r = 0; r < 4; ++r) { m2[mm][r] = -1e30f; ls[mm][r] = 0.f; }

  int nkv = 2 * qt + 2;
  for (int kvt = 0; kvt < nkv; ++kvt) {
    #pragma unroll
    for (int i = 0; i < 4; ++i) {
      int pos = ((i * 4 + w) << 10) + lane * 16;
      {
        int row = pos >> 8, csw = pos & 255;
        int csrc = csw ^ ((row & 7) << 4);
        gload16(k + (size_t)(bb * SEQ + kvt * 64 + row) * qk_stride + h * HD + (csrc >> 1),
                (char*)k_lds + ((i * 4 + w) << 10));
      }
      {
        int row = pos >> 7, csw = pos & 127;
        int csrc = csw ^ ((row & 7) << 4);
        gload16(vt + ((size_t)pr * HD + row) * SEQ + kvt * 64 + (csrc >> 1),
                (char*)vt_lds + ((i * 4 + w) << 10));
      }
    }
    __syncthreads();

    f32x4 s[2][4] = {};
    #pragma unroll
    for (int kk = 0; kk < 4; ++kk) {
      short8 bk[4];
      #pragma unroll
      for (int nn = 0; nn < 4; ++nn) {
        int row = nn * 16 + l15;
        int col = kk * 64 + g * 16;
        bk[nn] = *(const short8*)((const char*)k_lds + row * 256 + (col ^ ((row & 7) << 4)));
      }
      #pragma unroll
      for (int mm = 0; mm < 2; ++mm)
        #pragma unroll
        for (int nn = 0; nn < 4; ++nn)
          s[mm][nn] = __builtin_amdgcn_mfma_f32_16x16x32_bf16(aq[mm][kk], bk[nn], s[mm][nn], 0, 0, 0);
    }

    bool diag = (kvt >= 2 * qt);
    #pragma unroll
    for (int mm = 0; mm < 2; ++mm) {
      float mx[4] = {-1e30f, -1e30f, -1e30f, -1e30f};
      #pragma unroll
      for (int nn = 0; nn < 4; ++nn)
        #pragma unroll
        for (int r = 0; r < 4; ++r) {
          float sv = s[mm][nn][r] * SCL;
          if (diag) {
            int kvg = kvt * 64 + nn * 16 + l15;
            int qg = qrow_base + mm * 16 + g * 4 + r;
            if (kvg > qg) sv = -1e30f;
          }
          s[mm][nn][r] = sv;
          mx[r] = fmaxf(mx[r], sv);
        }
      #pragma unroll
      for (int r = 0; r < 4; ++r) {
        mx[r] = fmaxf(mx[r], __shfl_xor(mx[r], 1));
        mx[r] = fmaxf(mx[r], __shfl_xor(mx[r], 2));
        mx[r] = fmaxf(mx[r], __shfl_xor(mx[r], 4));
        mx[r] = fmaxf(mx[r], __shfl_xor(mx[r], 8));
        float mn = fmaxf(m2[mm][r], mx[r]);
        float al = exp2f(m2[mm][r] - mn);
        m2[mm][r] = mn;
        ls[mm][r] *= al;
        #pragma unroll
        for (int dd = 0; dd < 8; ++dd) o[mm][dd][r] *= al;
      }
      #pragma unroll
      for (int nn = 0; nn < 4; ++nn)
        #pragma unroll
        for (int r = 0; r < 4; ++r) {
          float pv = exp2f(s[mm][nn][r] - m2[mm][r]);
          ls[mm][r] += pv;
          int row = mm * 16 + g * 4 + r;
          int colb = (nn * 16 + l15) * 2;
          *(unsigned short*)((char*)p_lds[w] + row * 128 + (colb ^ (((row >> 1) & 7) << 4))) = f2b(pv);
        }
    }

    #pragma unroll
    for (int kk = 0; kk < 2; ++kk) {
      short8 pf[2], vf[8];
      #pragma unroll
      for (int mm = 0; mm < 2; ++mm) {
        int row = mm * 16 + l15;
        int col = kk * 64 + g * 16;
        pf[mm] = *(const short8*)((const char*)p_lds[w] + row * 128 + (col ^ (((row >> 1) & 7) << 4)));
      }
      #pragma unroll
      for (int dd = 0; dd < 8; ++dd) {
        int row = dd * 16 + l15;
        int col = kk * 64 + g * 16;
        vf[dd] = *(const short8*)((const char*)vt_lds + row * 128 + (col ^ ((row & 7) << 4)));
      }
      #pragma unroll
      for (int mm = 0; mm < 2; ++mm)
        #pragma unroll
        for (int dd = 0; dd < 8; ++dd)
          o[mm][dd] = __builtin_amdgcn_mfma_f32_16x16x32_bf16(pf[mm], vf[dd], o[mm][dd], 0, 0, 0);
    }
    __syncthreads();
  }

  #pragma unroll
  for (int mm = 0; mm < 2; ++mm) {
    float inv[4];
    #pragma unroll
    for (int r = 0; r < 4; ++r) {
      float tt = ls[mm][r];
      tt += __shfl_xor(tt, 1);
      tt += __shfl_xor(tt, 2);
      tt += __shfl_xor(tt, 4);
      tt += __shfl_xor(tt, 8);
      inv[r] = 1.f / tt;
    }
    #pragma unroll
    for (int dd = 0; dd < 8; ++dd)
      #pragma unroll
      for (int r = 0; r < 4; ++r) {
        size_t n = (size_t)(bb * SEQ + qrow_base + mm * 16 + g * 4 + r);
        int col = h * HD + dd * 16 + l15;
        ao[n * DM + col] = f2b(o[mm][dd][r] * inv[r]);
      }
  }
}

// ---------------------------------------------------------------- launch
extern "C" void kernel_launch(void* const* d_in, const int* in_sizes, int n_in,
                              void* d_out, int out_size, void* d_ws, size_t ws_size,
                              hipStream_t stream) {
  const int* tokens = (const int*)d_in[0];
  const float* tok_emb = (const float*)d_in[1];
  const float* wq = (const float*)d_in[2];
  const float* wk = (const float*)d_in[3];
  const float* wv = (const float*)d_in[4];
  const float* wo = (const float*)d_in[5];
  const float* attn_nw = (const float*)d_in[6];
  const float* ffn_nw = (const float*)d_in[7];
  const float* final_nw = (const float*)d_in[8];
  const float* w1 = (const float*)d_in[9];
  const float* w2 = (const float*)d_in[10];
  const float* out_proj = (const float*)d_in[11];
  float* out = (float*)d_out;

  char* ws = (char*)d_ws;
  size_t off = 0;
  auto alloc = [&](size_t bytes) -> char* {
    char* p = ws + off;
    off += (bytes + 255) & ~(size_t)255;
    return p;
  };
  unsigned short* wqkv_b = (unsigned short*)alloc((size_t)3 * DM * DM * 2);
  unsigned short* wo_b = (unsigned short*)alloc((size_t)DM * DM * 2);
  unsigned short* w1_b = (unsigned short*)alloc((size_t)DFF * DM * 2);
  unsigned short* w2_b = (unsigned short*)alloc((size_t)DM * DFF * 2);
  unsigned short* wop_b = (unsigned short*)alloc((size_t)NVOCAB * DM * 2);
  float* x = (float*)alloc((size_t)NTOK * DM * 4);
  unsigned short* xn = (unsigned short*)alloc((size_t)NTOK * DM * 2);
  unsigned short* qkv_b = (unsigned short*)alloc((size_t)NTOK * 3 * DM * 2);
  unsigned short* vt_b = (unsigned short*)alloc((size_t)NTOK * DM * 2);
  unsigned short* ao_b = (unsigned short*)alloc((size_t)NTOK * DM * 2);
  unsigned short* h1_b = qkv_b;  // alias: qkv+vt dead when h1 written

  auto conv = [&](const float* src, unsigned short* dst, size_t n) {
    int nq = (int)(n / 4);
    int grid = (nq + 255) / 256;
    if (grid > 4096) grid = 4096;
    k_f32_to_bf16<<<grid, 256, 0, stream>>>(src, dst, nq);
  };
  conv(wq, wqkv_b, (size_t)DM * DM);
  conv(wk, wqkv_b + (size_t)DM * DM, (size_t)DM * DM);
  conv(wv, wqkv_b + (size_t)2 * DM * DM, (size_t)DM * DM);
  conv(wo, wo_b, (size_t)DM * DM);
  conv(w1, w1_b, (size_t)DFF * DM);
  conv(w2, w2_b, (size_t)DM * DFF);
  conv(out_proj, wop_b, (size_t)NVOCAB * DM);

  k_embed<<<NTOK, 256, 0, stream>>>(tokens, tok_emb, x);
  k_rmsnorm<<<NTOK, 256, 0, stream>>>(x, attn_nw, xn);

  // fused QKV: [4096, 6144]
  k_gemm_nt<EPI_BF16><<<(NTOK / 256) * (3 * DM / 256), 512, 0, stream>>>(
      xn, wqkv_b, NTOK, 3 * DM, DM, nullptr, qkv_b, nullptr);

  k_transpose_v<<<32 * 32, 256, 0, stream>>>(qkv_b + 2 * DM, 3 * DM, vt_b);
  k_attn<<<32 * 16, 256, 0, stream>>>(qkv_b, qkv_b + DM, vt_b, ao_b, 3 * DM);

  k_gemm_nt<EPI_RESID><<<(NTOK / 256) * (DM / 256), 512, 0, stream>>>(
      ao_b, wo_b, NTOK, DM, DM, x, nullptr, x);

  k_rmsnorm<<<NTOK, 256, 0, stream>>>(x, ffn_nw, xn);
  k_gemm_nt<EPI_SILU><<<(NTOK / 256) * (DFF / 256), 512, 0, stream>>>(
      xn, w1_b, NTOK, DFF, DM, nullptr, h1_b, nullptr);
  k_gemm_nt<EPI_RESID><<<(NTOK / 256) * (DM / 256), 512, 0, stream>>>(
      h1_b, w2_b, NTOK, DM, DFF, x, nullptr, x);

  k_rmsnorm<<<NTOK, 256, 0, stream>>>(x, final_nw, xn);
  k_gemm_nt<EPI_F32><<<(NTOK / 256) * (NVOCAB / 256), 512, 0, stream>>>(
      xn, wop_b, NTOK, NVOCAB, DM, out, nullptr, nullptr);
}

// Round 5
// 1419.669 us; speedup vs baseline: 1.2910x; 1.0272x over previous
//
#include <hip/hip_runtime.h>
#include <stdint.h>

#define DM     2048
#define NHE    16
#define DFF    8192
#define NBATCH 2
#define SEQ    2048
#define NTOK   4096
#define HD     128
#define NVOCAB 32000

typedef __attribute__((ext_vector_type(8))) short short8;
typedef __attribute__((ext_vector_type(4))) float f32x4;
typedef __attribute__((ext_vector_type(4))) unsigned short u16x4;

static __device__ __forceinline__ unsigned short f2b(float f) {
  union { float f; uint32_t u; } v; v.f = f;
  return (unsigned short)((v.u + 0x7FFFu + ((v.u >> 16) & 1u)) >> 16);
}

static __device__ __forceinline__ void gload16(const void* g, void* l) {
  __builtin_amdgcn_global_load_lds(
      (const __attribute__((address_space(1))) unsigned int*)g,
      (__attribute__((address_space(3))) unsigned int*)l, 16, 0, 0);
}

// ---------------------------------------------------------------- conversions
__global__ void k_f32_to_bf16(const float* __restrict__ in,
                              unsigned short* __restrict__ out, int nq) {
  int i = blockIdx.x * blockDim.x + threadIdx.x;
  int stride = gridDim.x * blockDim.x;
  for (; i < nq; i += stride) {
    float4 v = ((const float4*)in)[i];
    u16x4 o;
    o.x = f2b(v.x); o.y = f2b(v.y); o.z = f2b(v.z); o.w = f2b(v.w);
    ((u16x4*)out)[i] = o;
  }
}

// ---------------------------------------------------------------- embedding
__global__ void k_embed(const int* __restrict__ tok,
                        const float* __restrict__ emb, float* __restrict__ x) {
  int n = blockIdx.x;
  int t = tok[n];
  const float4* src = (const float4*)(emb + (size_t)t * DM);
  float4* dst = (float4*)(x + (size_t)n * DM);
  for (int i = threadIdx.x; i < DM / 4; i += blockDim.x) dst[i] = src[i];
}

// ---------------------------------------------------------------- rmsnorm
__global__ void k_rmsnorm(const float* __restrict__ x, const float* __restrict__ wt,
                          unsigned short* __restrict__ out) {
  int n = blockIdx.x;
  const float* row = x + (size_t)n * DM;
  float ss = 0.f;
  #pragma unroll
  for (int it = 0; it < 2; ++it) {
    int i = threadIdx.x * 4 + it * 1024;
    float4 v = *(const float4*)(row + i);
    ss += v.x * v.x + v.y * v.y + v.z * v.z + v.w * v.w;
  }
  #pragma unroll
  for (int m = 1; m < 64; m <<= 1) ss += __shfl_xor(ss, m);
  __shared__ float p[4];
  if ((threadIdx.x & 63) == 0) p[threadIdx.x >> 6] = ss;
  __syncthreads();
  float inv = rsqrtf((p[0] + p[1] + p[2] + p[3]) * (1.f / DM) + 1e-6f);
  #pragma unroll
  for (int it = 0; it < 2; ++it) {
    int i = threadIdx.x * 4 + it * 1024;
    float4 v = *(const float4*)(row + i);
    float4 w4 = *(const float4*)(wt + i);
    u16x4 o;
    o.x = f2b(v.x * w4.x * inv); o.y = f2b(v.y * w4.y * inv);
    o.z = f2b(v.z * w4.z * inv); o.w = f2b(v.w * w4.w * inv);
    *(u16x4*)(out + (size_t)n * DM + i) = o;
  }
}

// ---------------------------------------------------------------- GEMM (NT)
// C[M,N] = A[M,K] * B[N,K]^T ; bf16 in, f32 accum.
// TMx256 tile, BK=64, 8 waves (2Mx4N), per-wave (TM/2)x64 out.
// Staging/vmcnt skeleton identical to proven r3/r4:
//   stage(kt+1) -> vmcnt(loads) -> bar -> [4 quadrant phases] .
// Each quadrant phase: af reads; bar; lgkm(0); setprio+MFMA; bar  (T3).
// GN: bn-group width for L3 residency (bn-fastest within group).
#define EPI_BF16  0
#define EPI_RESID 1
#define EPI_SILU  2
#define EPI_F32   3

template <int EPI, int TM>
__launch_bounds__(512, 2)
__global__ void k_gemm_nt(const unsigned short* __restrict__ A,
                          const unsigned short* __restrict__ Bm,
                          int M, int N, int K, int GN,
                          float* __restrict__ Cf, unsigned short* __restrict__ Cb,
                          const float* __restrict__ R) {
  constexpr int ALDS = TM * 64;            // ushorts in A region
  constexpr int MM = TM / 32;              // M-frags per wave (8 or 4)
  constexpr int MQ = MM / 4;               // M-frags per quadrant (2 or 1)
  __shared__ unsigned short lds[2 * (ALDS + 16384)];

  int nbm = M / TM;
  int nbn = N >> 8;
  int nwg = gridDim.x;
  int bid = blockIdx.x;
  int cpx = nwg >> 3;                       // all grids are multiples of 8
  bid = (bid & 7) * cpx + (bid >> 3);       // XCD-bijective swizzle
  int grpsz = nbm * GN;
  int gg = bid / grpsz, rr = bid % grpsz;
  int bm = rr / GN;
  int bn = gg * GN + rr % GN;               // bn-fastest within group
  (void)nbn;
  int t = threadIdx.x, w = t >> 6, lane = t & 63;
  int wr = w >> 2, wc = w & 3;              // 2 (M) x 4 (N) waves
  int g = lane >> 4, l15 = lane & 15;

  f32x4 acc[MM][4] = {};

  size_t abase = (size_t)(bm * TM) * K;
  size_t bbase = (size_t)(bn * 256) * K;
  int nkt = K >> 6;

  auto stage = [&](int buf, int kt) {
    unsigned short* dst = lds + buf * (ALDS + 16384);
    int k0 = kt << 6;
    #pragma unroll
    for (int i = 0; i < TM / 64; ++i) {
      int pos = (i * 512 + t) << 4;          // byte pos in A region
      int row = pos >> 7, colb = pos & 127;
      int csrc = colb ^ ((row & 7) << 4);
      gload16(A + abase + (size_t)row * K + k0 + (csrc >> 1), (char*)dst + pos);
    }
    #pragma unroll
    for (int i = 0; i < 4; ++i) {
      int pos = (i * 512 + t) << 4;          // byte pos in 32KB B region
      int row = pos >> 7, colb = pos & 127;
      int csrc = colb ^ ((row & 7) << 4);
      gload16(Bm + bbase + (size_t)row * K + k0 + (csrc >> 1),
              (char*)(dst + ALDS) + pos);
    }
  };

  stage(0, 0);
  for (int kt = 0; kt < nkt; ++kt) {
    int cur = kt & 1;
    if (kt + 1 < nkt) {
      stage(1 - cur, kt + 1);
      if constexpr (TM == 256) {
        asm volatile("s_waitcnt vmcnt(8)" ::: "memory");
      } else {
        asm volatile("s_waitcnt vmcnt(6)" ::: "memory");
      }
    } else {
      asm volatile("s_waitcnt vmcnt(0)" ::: "memory");
    }
    __builtin_amdgcn_s_barrier();
    __builtin_amdgcn_sched_barrier(0);

    const unsigned short* abuf = lds + cur * (ALDS + 16384);
    const unsigned short* bbuf = abuf + ALDS;

    short8 bfr[4][2];
    #pragma unroll
    for (int nn = 0; nn < 4; ++nn)
      #pragma unroll
      for (int kk = 0; kk < 2; ++kk) {
        int row = wc * 64 + nn * 16 + l15;
        int col = kk * 64 + g * 16;
        bfr[nn][kk] = *(const short8*)((const char*)bbuf + row * 128 + (col ^ ((row & 7) << 4)));
      }

    #pragma unroll
    for (int q = 0; q < 4; ++q) {
      short8 af[MQ][2];
      #pragma unroll
      for (int mi = 0; mi < MQ; ++mi)
        #pragma unroll
        for (int kk = 0; kk < 2; ++kk) {
          int row = wr * (TM / 2) + (q * MQ + mi) * 16 + l15;
          int col = kk * 64 + g * 16;
          af[mi][kk] = *(const short8*)((const char*)abuf + row * 128 + (col ^ ((row & 7) << 4)));
        }
      __builtin_amdgcn_s_barrier();
      asm volatile("s_waitcnt lgkmcnt(0)" ::: "memory");
      __builtin_amdgcn_sched_barrier(0);
      __builtin_amdgcn_s_setprio(1);
      #pragma unroll
      for (int mi = 0; mi < MQ; ++mi)
        #pragma unroll
        for (int nn = 0; nn < 4; ++nn)
          #pragma unroll
          for (int kk = 0; kk < 2; ++kk)
            acc[q * MQ + mi][nn] =
                __builtin_amdgcn_mfma_f32_16x16x32_bf16(af[mi][kk], bfr[nn][kk],
                                                        acc[q * MQ + mi][nn], 0, 0, 0);
      __builtin_amdgcn_s_setprio(0);
      __builtin_amdgcn_sched_barrier(0);
      __builtin_amdgcn_s_barrier();
    }
  }

  #pragma unroll
  for (int mm = 0; mm < MM; ++mm) {
    #pragma unroll
    for (int nn = 0; nn < 4; ++nn) {
      #pragma unroll
      for (int r = 0; r < 4; ++r) {
        int grow = bm * TM + wr * (TM / 2) + mm * 16 + g * 4 + r;
        int gcol = bn * 256 + wc * 64 + nn * 16 + l15;
        size_t off = (size_t)grow * N + gcol;
        float v = acc[mm][nn][r];
        if (EPI == EPI_BF16) {
          Cb[off] = f2b(v);
        } else if (EPI == EPI_RESID) {
          Cf[off] = R[off] + v;
        } else if (EPI == EPI_SILU) {
          float s = 1.f / (1.f + __expf(-v));
          Cb[off] = f2b(v * s);
        } else {
          Cf[off] = v;
        }
      }
    }
  }
}

// ---------------------------------------------------------------- V transpose
__global__ void k_transpose_v(const unsigned short* __restrict__ v, int vstride,
                              unsigned short* __restrict__ vt) {
  __shared__ unsigned short tile[64][136];
  int pr = blockIdx.x >> 5;     // pair
  int st = blockIdx.x & 31;     // s-tile of 64
  int bb = pr >> 4, h = pr & 15;
  int row = threadIdx.x >> 2;
  int cq = threadIdx.x & 3;
  const unsigned short* src =
      v + (size_t)(bb * SEQ + st * 64 + row) * vstride + h * HD + cq * 32;
  #pragma unroll
  for (int j = 0; j < 4; ++j)
    *(short8*)&tile[row][cq * 32 + j * 8] = *(const short8*)(src + j * 8);
  __syncthreads();
  int d = threadIdx.x >> 1;
  int sh = threadIdx.x & 1;
  unsigned short tmp[32];
  #pragma unroll
  for (int j = 0; j < 32; ++j) tmp[j] = tile[sh * 32 + j][d];
  unsigned short* dst = vt + ((size_t)pr * HD + d) * SEQ + st * 64 + sh * 32;
  #pragma unroll
  for (int j = 0; j < 4; ++j)
    *(short8*)(dst + j * 8) = *(const short8*)&tmp[j * 8];
}

// ---------------------------------------------------------------- attention
__launch_bounds__(256)
__global__ void k_attn(const unsigned short* __restrict__ q,
                       const unsigned short* __restrict__ k,
                       const unsigned short* __restrict__ vt,
                       unsigned short* __restrict__ ao, int qk_stride) {
  __shared__ unsigned short k_lds[64 * 128];
  __shared__ unsigned short vt_lds[128 * 64];
  __shared__ unsigned short p_lds[4][32 * 64];

  int bid = blockIdx.x;
  int pr = bid >> 4;
  int qt = 15 - (bid & 15);
  int bb = pr >> 4, h = pr & 15;
  int t = threadIdx.x, w = t >> 6, lane = t & 63;
  int g = lane >> 4, l15 = lane & 15;
  const float SCL = 0.08838834764831845f * 1.4426950408889634f;

  int qrow_base = qt * 128 + w * 32;
  short8 aq[2][4];
  #pragma unroll
  for (int mm = 0; mm < 2; ++mm) {
    size_t n = (size_t)(bb * SEQ + qrow_base + mm * 16 + l15);
    #pragma unroll
    for (int kk = 0; kk < 4; ++kk)
      aq[mm][kk] = *(const short8*)(q + n * qk_stride + h * HD + kk * 32 + g * 8);
  }

  f32x4 o[2][8] = {};
  float m2[2][4], ls[2][4];
  #pragma unroll
  for (int mm = 0; mm < 2; ++mm)
    #pragma unroll
    for (int r = 0; r < 4; ++r) { m2[mm][r] = -1e30f; ls[mm][r] = 0.f; }

  int nkv = 2 * qt + 2;
  for (int kvt = 0; kvt < nkv; ++kvt) {
    #pragma unroll
    for (int i = 0; i < 4; ++i) {
      int pos = ((i * 4 + w) << 10) + lane * 16;
      {
        int row = pos >> 8, csw = pos & 255;
        int csrc = csw ^ ((row & 7) << 4);
        gload16(k + (size_t)(bb * SEQ + kvt * 64 + row) * qk_stride + h * HD + (csrc >> 1),
                (char*)k_lds + ((i * 4 + w) << 10));
      }
      {
        int row = pos >> 7, csw = pos & 127;
        int csrc = csw ^ ((row & 7) << 4);
        gload16(vt + ((size_t)pr * HD + row) * SEQ + kvt * 64 + (csrc >> 1),
                (char*)vt_lds + ((i * 4 + w) << 10));
      }
    }
    __syncthreads();

    f32x4 s[2][4] = {};
    #pragma unroll
    for (int kk = 0; kk < 4; ++kk) {
      short8 bk[4];
      #pragma unroll
      for (int nn = 0; nn < 4; ++nn) {
        int row = nn * 16 + l15;
        int col = kk * 64 + g * 16;
        bk[nn] = *(const short8*)((const char*)k_lds + row * 256 + (col ^ ((row & 7) << 4)));
      }
      #pragma unroll
      for (int mm = 0; mm < 2; ++mm)
        #pragma unroll
        for (int nn = 0; nn < 4; ++nn)
          s[mm][nn] = __builtin_amdgcn_mfma_f32_16x16x32_bf16(aq[mm][kk], bk[nn], s[mm][nn], 0, 0, 0);
    }

    bool diag = (kvt >= 2 * qt);
    #pragma unroll
    for (int mm = 0; mm < 2; ++mm) {
      float mx[4] = {-1e30f, -1e30f, -1e30f, -1e30f};
      #pragma unroll
      for (int nn = 0; nn < 4; ++nn)
        #pragma unroll
        for (int r = 0; r < 4; ++r) {
          float sv = s[mm][nn][r] * SCL;
          if (diag) {
            int kvg = kvt * 64 + nn * 16 + l15;
            int qg = qrow_base + mm * 16 + g * 4 + r;
            if (kvg > qg) sv = -1e30f;
          }
          s[mm][nn][r] = sv;
          mx[r] = fmaxf(mx[r], sv);
        }
      #pragma unroll
      for (int r = 0; r < 4; ++r) {
        mx[r] = fmaxf(mx[r], __shfl_xor(mx[r], 1));
        mx[r] = fmaxf(mx[r], __shfl_xor(mx[r], 2));
        mx[r] = fmaxf(mx[r], __shfl_xor(mx[r], 4));
        mx[r] = fmaxf(mx[r], __shfl_xor(mx[r], 8));
        float mn = fmaxf(m2[mm][r], mx[r]);
        float al = exp2f(m2[mm][r] - mn);
        m2[mm][r] = mn;
        ls[mm][r] *= al;
        #pragma unroll
        for (int dd = 0; dd < 8; ++dd) o[mm][dd][r] *= al;
      }
      #pragma unroll
      for (int nn = 0; nn < 4; ++nn)
        #pragma unroll
        for (int r = 0; r < 4; ++r) {
          float pv = exp2f(s[mm][nn][r] - m2[mm][r]);
          ls[mm][r] += pv;
          int row = mm * 16 + g * 4 + r;
          int colb = (nn * 16 + l15) * 2;
          *(unsigned short*)((char*)p_lds[w] + row * 128 + (colb ^ (((row >> 1) & 7) << 4))) = f2b(pv);
        }
    }

    #pragma unroll
    for (int kk = 0; kk < 2; ++kk) {
      short8 pf[2], vf[8];
      #pragma unroll
      for (int mm = 0; mm < 2; ++mm) {
        int row = mm * 16 + l15;
        int col = kk * 64 + g * 16;
        pf[mm] = *(const short8*)((const char*)p_lds[w] + row * 128 + (col ^ (((row >> 1) & 7) << 4)));
      }
      #pragma unroll
      for (int dd = 0; dd < 8; ++dd) {
        int row = dd * 16 + l15;
        int col = kk * 64 + g * 16;
        vf[dd] = *(const short8*)((const char*)vt_lds + row * 128 + (col ^ ((row & 7) << 4)));
      }
      #pragma unroll
      for (int mm = 0; mm < 2; ++mm)
        #pragma unroll
        for (int dd = 0; dd < 8; ++dd)
          o[mm][dd] = __builtin_amdgcn_mfma_f32_16x16x32_bf16(pf[mm], vf[dd], o[mm][dd], 0, 0, 0);
    }
    __syncthreads();
  }

  #pragma unroll
  for (int mm = 0; mm < 2; ++mm) {
    float inv[4];
    #pragma unroll
    for (int r = 0; r < 4; ++r) {
      float tt = ls[mm][r];
      tt += __shfl_xor(tt, 1);
      tt += __shfl_xor(tt, 2);
      tt += __shfl_xor(tt, 4);
      tt += __shfl_xor(tt, 8);
      inv[r] = 1.f / tt;
    }
    #pragma unroll
    for (int dd = 0; dd < 8; ++dd)
      #pragma unroll
      for (int r = 0; r < 4; ++r) {
        size_t n = (size_t)(bb * SEQ + qrow_base + mm * 16 + g * 4 + r);
        int col = h * HD + dd * 16 + l15;
        ao[n * DM + col] = f2b(o[mm][dd][r] * inv[r]);
      }
  }
}

// ---------------------------------------------------------------- launch
extern "C" void kernel_launch(void* const* d_in, const int* in_sizes, int n_in,
                              void* d_out, int out_size, void* d_ws, size_t ws_size,
                              hipStream_t stream) {
  const int* tokens = (const int*)d_in[0];
  const float* tok_emb = (const float*)d_in[1];
  const float* wq = (const float*)d_in[2];
  const float* wk = (const float*)d_in[3];
  const float* wv = (const float*)d_in[4];
  const float* wo = (const float*)d_in[5];
  const float* attn_nw = (const float*)d_in[6];
  const float* ffn_nw = (const float*)d_in[7];
  const float* final_nw = (const float*)d_in[8];
  const float* w1 = (const float*)d_in[9];
  const float* w2 = (const float*)d_in[10];
  const float* out_proj = (const float*)d_in[11];
  float* out = (float*)d_out;

  char* ws = (char*)d_ws;
  size_t off = 0;
  auto alloc = [&](size_t bytes) -> char* {
    char* p = ws + off;
    off += (bytes + 255) & ~(size_t)255;
    return p;
  };
  unsigned short* wqkv_b = (unsigned short*)alloc((size_t)3 * DM * DM * 2);
  unsigned short* wo_b = (unsigned short*)alloc((size_t)DM * DM * 2);
  unsigned short* w1_b = (unsigned short*)alloc((size_t)DFF * DM * 2);
  unsigned short* w2_b = (unsigned short*)alloc((size_t)DM * DFF * 2);
  unsigned short* wop_b = (unsigned short*)alloc((size_t)NVOCAB * DM * 2);
  float* x = (float*)alloc((size_t)NTOK * DM * 4);
  unsigned short* xn = (unsigned short*)alloc((size_t)NTOK * DM * 2);
  unsigned short* qkv_b = (unsigned short*)alloc((size_t)NTOK * 3 * DM * 2);
  unsigned short* vt_b = (unsigned short*)alloc((size_t)NTOK * DM * 2);
  unsigned short* ao_b = (unsigned short*)alloc((size_t)NTOK * DM * 2);
  unsigned short* h1_b = qkv_b;  // alias: qkv+vt dead when h1 written

  auto conv = [&](const float* src, unsigned short* dst, size_t n) {
    int nq = (int)(n / 4);
    int grid = (nq + 255) / 256;
    if (grid > 4096) grid = 4096;
    k_f32_to_bf16<<<grid, 256, 0, stream>>>(src, dst, nq);
  };
  conv(wq, wqkv_b, (size_t)DM * DM);
  conv(wk, wqkv_b + (size_t)DM * DM, (size_t)DM * DM);
  conv(wv, wqkv_b + (size_t)2 * DM * DM, (size_t)DM * DM);
  conv(wo, wo_b, (size_t)DM * DM);
  conv(w1, w1_b, (size_t)DFF * DM);
  conv(w2, w2_b, (size_t)DM * DFF);
  conv(out_proj, wop_b, (size_t)NVOCAB * DM);

  k_embed<<<NTOK, 256, 0, stream>>>(tokens, tok_emb, x);
  k_rmsnorm<<<NTOK, 256, 0, stream>>>(x, attn_nw, xn);

  // fused QKV: [4096, 6144]
  k_gemm_nt<EPI_BF16, 256><<<(NTOK / 256) * (3 * DM / 256), 512, 0, stream>>>(
      xn, wqkv_b, NTOK, 3 * DM, DM, 3 * DM / 256, nullptr, qkv_b, nullptr);

  k_transpose_v<<<32 * 32, 256, 0, stream>>>(qkv_b + 2 * DM, 3 * DM, vt_b);
  k_attn<<<32 * 16, 256, 0, stream>>>(qkv_b, qkv_b + DM, vt_b, ao_b, 3 * DM);

  k_gemm_nt<EPI_RESID, 128><<<(NTOK / 128) * (DM / 256), 512, 0, stream>>>(
      ao_b, wo_b, NTOK, DM, DM, DM / 256, x, nullptr, x);

  k_rmsnorm<<<NTOK, 256, 0, stream>>>(x, ffn_nw, xn);
  k_gemm_nt<EPI_SILU, 256><<<(NTOK / 256) * (DFF / 256), 512, 0, stream>>>(
      xn, w1_b, NTOK, DFF, DM, DFF / 256, nullptr, h1_b, nullptr);
  k_gemm_nt<EPI_RESID, 128><<<(NTOK / 128) * (DM / 256), 512, 0, stream>>>(
      h1_b, w2_b, NTOK, DM, DFF, DM / 256, x, nullptr, x);

  k_rmsnorm<<<NTOK, 256, 0, stream>>>(x, final_nw, xn);
  // logits: GN=25 -> B working set 25*256 cols * 2048 * 2B = 26 MB (L3-resident)
  k_gemm_nt<EPI_F32, 256><<<(NTOK / 256) * (NVOCAB / 256), 512, 0, stream>>>(
      xn, wop_b, NTOK, NVOCAB, DM, 25, out, nullptr, nullptr);
}

// Round 7
// 1316.027 us; speedup vs baseline: 1.3926x; 1.0788x over previous
//
#include <hip/hip_runtime.h>
#include <stdint.h>

#define DM     2048
#define NHE    16
#define DFF    8192
#define NBATCH 2
#define SEQ    2048
#define NTOK   4096
#define HD     128
#define NVOCAB 32000

typedef __attribute__((ext_vector_type(8))) short short8;
typedef __attribute__((ext_vector_type(4))) float f32x4;
typedef __attribute__((ext_vector_type(4))) unsigned short u16x4;

static __device__ __forceinline__ unsigned short f2b(float f) {
  union { float f; uint32_t u; } v; v.f = f;
  return (unsigned short)((v.u + 0x7FFFu + ((v.u >> 16) & 1u)) >> 16);
}

static __device__ __forceinline__ void gload16(const void* g, void* l) {
  __builtin_amdgcn_global_load_lds(
      (const __attribute__((address_space(1))) unsigned int*)g,
      (__attribute__((address_space(3))) unsigned int*)l, 16, 0, 0);
}

// ---------------------------------------------------------------- conversions
__global__ void k_f32_to_bf16(const float* __restrict__ in,
                              unsigned short* __restrict__ out, int nq) {
  int i = blockIdx.x * blockDim.x + threadIdx.x;
  int stride = gridDim.x * blockDim.x;
  for (; i < nq; i += stride) {
    float4 v = ((const float4*)in)[i];
    u16x4 o;
    o.x = f2b(v.x); o.y = f2b(v.y); o.z = f2b(v.z); o.w = f2b(v.w);
    ((u16x4*)out)[i] = o;
  }
}

// ---------------------------------------------------------------- embedding
__global__ void k_embed(const int* __restrict__ tok,
                        const float* __restrict__ emb, float* __restrict__ x) {
  int n = blockIdx.x;
  int t = tok[n];
  const float4* src = (const float4*)(emb + (size_t)t * DM);
  float4* dst = (float4*)(x + (size_t)n * DM);
  for (int i = threadIdx.x; i < DM / 4; i += blockDim.x) dst[i] = src[i];
}

// ---------------------------------------------------------------- rmsnorm
__global__ void k_rmsnorm(const float* __restrict__ x, const float* __restrict__ wt,
                          unsigned short* __restrict__ out) {
  int n = blockIdx.x;
  const float* row = x + (size_t)n * DM;
  float ss = 0.f;
  #pragma unroll
  for (int it = 0; it < 2; ++it) {
    int i = threadIdx.x * 4 + it * 1024;
    float4 v = *(const float4*)(row + i);
    ss += v.x * v.x + v.y * v.y + v.z * v.z + v.w * v.w;
  }
  #pragma unroll
  for (int m = 1; m < 64; m <<= 1) ss += __shfl_xor(ss, m);
  __shared__ float p[4];
  if ((threadIdx.x & 63) == 0) p[threadIdx.x >> 6] = ss;
  __syncthreads();
  float inv = rsqrtf((p[0] + p[1] + p[2] + p[3]) * (1.f / DM) + 1e-6f);
  #pragma unroll
  for (int it = 0; it < 2; ++it) {
    int i = threadIdx.x * 4 + it * 1024;
    float4 v = *(const float4*)(row + i);
    float4 w4 = *(const float4*)(wt + i);
    u16x4 o;
    o.x = f2b(v.x * w4.x * inv); o.y = f2b(v.y * w4.y * inv);
    o.z = f2b(v.z * w4.z * inv); o.w = f2b(v.w * w4.w * inv);
    *(u16x4*)(out + (size_t)n * DM + i) = o;
  }
}

#define EPI_BF16  0
#define EPI_RESID 1
#define EPI_SILU  2
#define EPI_F32   3

// ---------------------------------------------------------------- GEMM 256x256 4-phase pipelined
// C[M,N] = A[M,K]*B[N,K]^T. 8 waves (2M x 4N), per-wave 128x64, BK=64.
// Double-buffered 128KB LDS. Per K-tile 4 phases; stage counts [5,1,1,1]
// (B-full + A-quad0 at phase0; A-quad q at phase q). Counted vmcnt [7,7,7,3]
// publishes each staged load exactly at its consumer's preceding barrier
// (in-order vmcnt retirement). One iteration-end barrier = WAR guard.
#define PHASE(Q, VM)                                                          \
  {                                                                           \
    short8 af[2][2];                                                          \
    _Pragma("unroll")                                                         \
    for (int mi = 0; mi < 2; ++mi)                                            \
      _Pragma("unroll")                                                       \
      for (int kk = 0; kk < 2; ++kk) {                                        \
        int row = wr * 128 + (2 * (Q) + mi) * 16 + l15;                       \
        int col = kk * 64 + g * 16;                                           \
        af[mi][kk] = *(const short8*)((const char*)abuf + row * 128 +         \
                                      (col ^ ((row & 7) << 4)));              \
      }                                                                       \
    if ((Q) == 0) {                                                           \
      _Pragma("unroll")                                                       \
      for (int nn = 0; nn < 4; ++nn)                                          \
        _Pragma("unroll")                                                     \
        for (int kk = 0; kk < 2; ++kk) {                                      \
          int row = wc * 64 + nn * 16 + l15;                                  \
          int col = kk * 64 + g * 16;                                         \
          bfr[nn][kk] = *(const short8*)((const char*)bbuf + row * 128 +      \
                                         (col ^ ((row & 7) << 4)));           \
        }                                                                     \
    }                                                                         \
    if (kt + 1 < nkt) {                                                       \
      if ((Q) == 0) {                                                         \
        _Pragma("unroll")                                                     \
        for (int i = 0; i < 4; ++i) {                                         \
          int pos = (i * 512 + t) << 4;                                       \
          int row = pos >> 7, colb = pos & 127;                               \
          int csrc = colb ^ ((row & 7) << 4);                                 \
          gload16(Bm + bbase + (size_t)row * K + k0n + (csrc >> 1),           \
                  (char*)(nbuf + 16384) + pos);                               \
        }                                                                     \
      }                                                                       \
      {                                                                       \
        int pos = (t < 256) ? ((Q) * 4096 + t * 16)                           \
                            : (16384 + (Q) * 4096 + (t - 256) * 16);          \
        int row = pos >> 7, colb = pos & 127;                                 \
        int csrc = colb ^ ((row & 7) << 4);                                   \
        gload16(A + abase + (size_t)row * K + k0n + (csrc >> 1),              \
                (char*)nbuf + pos);                                           \
      }                                                                       \
      asm volatile("s_waitcnt vmcnt(" VM ")" ::: "memory");                   \
    } else {                                                                  \
      if ((Q) == 0) asm volatile("s_waitcnt vmcnt(0)" ::: "memory");          \
    }                                                                         \
    __builtin_amdgcn_s_barrier();                                             \
    asm volatile("s_waitcnt lgkmcnt(0)" ::: "memory");                        \
    __builtin_amdgcn_sched_barrier(0);                                        \
    __builtin_amdgcn_s_setprio(1);                                            \
    _Pragma("unroll")                                                         \
    for (int mi = 0; mi < 2; ++mi)                                            \
      _Pragma("unroll")                                                       \
      for (int nn = 0; nn < 4; ++nn)                                          \
        _Pragma("unroll")                                                     \
        for (int kk = 0; kk < 2; ++kk)                                        \
          acc[2 * (Q) + mi][nn] = __builtin_amdgcn_mfma_f32_16x16x32_bf16(    \
              af[mi][kk], bfr[nn][kk], acc[2 * (Q) + mi][nn], 0, 0, 0);       \
    __builtin_amdgcn_s_setprio(0);                                            \
    __builtin_amdgcn_sched_barrier(0);                                        \
  }

template <int EPI>
__launch_bounds__(512, 2)
__global__ void k_gemm8p(const unsigned short* __restrict__ A,
                         const unsigned short* __restrict__ Bm,
                         int M, int N, int K, int GN,
                         float* __restrict__ Cf, unsigned short* __restrict__ Cb,
                         const float* __restrict__ R) {
  __shared__ unsigned short lds[2][32768];   // per buf: A 32KB + B 32KB
  int nbm = M >> 8;
  int nwg = gridDim.x;
  int bid = blockIdx.x;
  int cpx = nwg >> 3;
  bid = (bid & 7) * cpx + (bid >> 3);        // XCD-bijective swizzle
  int grpsz = nbm * GN;
  int gg = bid / grpsz, rr = bid % grpsz;
  int bm = rr / GN;
  int bn = gg * GN + rr % GN;                // bn-fastest within L3 group
  int t = threadIdx.x, w = t >> 6, lane = t & 63;
  int wr = w >> 2, wc = w & 3;
  int g = lane >> 4, l15 = lane & 15;

  f32x4 acc[8][4] = {};
  size_t abase = (size_t)(bm * 256) * K;
  size_t bbase = (size_t)(bn * 256) * K;
  int nkt = K >> 6;

  // prologue: stage tile 0 fully (A 32KB + B 32KB), drain, barrier
  {
    unsigned short* nbuf = lds[0];
    #pragma unroll
    for (int i = 0; i < 4; ++i) {
      int pos = (i * 512 + t) << 4;
      int row = pos >> 7, colb = pos & 127;
      int csrc = colb ^ ((row & 7) << 4);
      gload16(Bm + bbase + (size_t)row * K + (csrc >> 1), (char*)(nbuf + 16384) + pos);
    }
    #pragma unroll
    for (int i = 0; i < 4; ++i) {
      int pos = (i * 512 + t) << 4;
      int row = pos >> 7, colb = pos & 127;
      int csrc = colb ^ ((row & 7) << 4);
      gload16(A + abase + (size_t)row * K + (csrc >> 1), (char*)nbuf + pos);
    }
    asm volatile("s_waitcnt vmcnt(0)" ::: "memory");
    __builtin_amdgcn_s_barrier();
  }

  for (int kt = 0; kt < nkt; ++kt) {
    int cur = kt & 1;
    const unsigned short* abuf = lds[cur];
    const unsigned short* bbuf = abuf + 16384;
    unsigned short* nbuf = lds[1 - cur];
    int k0n = (kt + 1) << 6;
    short8 bfr[4][2];
    PHASE(0, "7")
    PHASE(1, "7")
    PHASE(2, "7")
    PHASE(3, "3")
    __builtin_amdgcn_s_barrier();            // iteration-end WAR guard
  }

  #pragma unroll
  for (int mm = 0; mm < 8; ++mm) {
    #pragma unroll
    for (int nn = 0; nn < 4; ++nn) {
      #pragma unroll
      for (int r = 0; r < 4; ++r) {
        int grow = bm * 256 + wr * 128 + mm * 16 + g * 4 + r;
        int gcol = bn * 256 + wc * 64 + nn * 16 + l15;
        size_t off = (size_t)grow * N + gcol;
        float v = acc[mm][nn][r];
        if (EPI == EPI_BF16) {
          Cb[off] = f2b(v);
        } else if (EPI == EPI_RESID) {
          Cf[off] = R[off] + v;
        } else if (EPI == EPI_SILU) {
          float s = 1.f / (1.f + __expf(-v));
          Cb[off] = f2b(v * s);
        } else {
          __builtin_nontemporal_store(v, &Cf[off]);   // keep C out of L3
        }
      }
    }
  }
}

// ---------------------------------------------------------------- GEMM 128x256 simple (r4-style)
template <int EPI>
__launch_bounds__(512, 2)
__global__ void k_gemm_sm(const unsigned short* __restrict__ A,
                          const unsigned short* __restrict__ Bm,
                          int M, int N, int K,
                          float* __restrict__ Cf, unsigned short* __restrict__ Cb,
                          const float* __restrict__ R) {
  __shared__ unsigned short lds[2][24576];   // per buf: A 16KB + B 32KB
  int nbn = N >> 8;
  int nwg = gridDim.x;
  int bid = blockIdx.x;
  int cpx = nwg >> 3;
  bid = (bid & 7) * cpx + (bid >> 3);
  int bm = bid / nbn, bn = bid % nbn;
  int t = threadIdx.x, w = t >> 6, lane = t & 63;
  int wr = w >> 2, wc = w & 3;               // 2 (M) x 4 (N)
  int g = lane >> 4, l15 = lane & 15;

  f32x4 acc[4][4] = {};
  size_t abase = (size_t)(bm * 128) * K;
  size_t bbase = (size_t)(bn * 256) * K;
  int nkt = K >> 6;

  auto stage = [&](int buf, int kt) {
    unsigned short* dst = lds[buf];
    int k0 = kt << 6;
    #pragma unroll
    for (int i = 0; i < 2; ++i) {
      int pos = (i * 512 + t) << 4;
      int row = pos >> 7, colb = pos & 127;
      int csrc = colb ^ ((row & 7) << 4);
      gload16(A + abase + (size_t)row * K + k0 + (csrc >> 1), (char*)dst + pos);
    }
    #pragma unroll
    for (int i = 0; i < 4; ++i) {
      int pos = (i * 512 + t) << 4;
      int row = pos >> 7, colb = pos & 127;
      int csrc = colb ^ ((row & 7) << 4);
      gload16(Bm + bbase + (size_t)row * K + k0 + (csrc >> 1),
              (char*)(dst + 8192) + pos);
    }
  };

  stage(0, 0);
  for (int kt = 0; kt < nkt; ++kt) {
    int cur = kt & 1;
    if (kt + 1 < nkt) {
      stage(1 - cur, kt + 1);
      asm volatile("s_waitcnt vmcnt(6)" ::: "memory");
    } else {
      asm volatile("s_waitcnt vmcnt(0)" ::: "memory");
    }
    __builtin_amdgcn_s_barrier();
    __builtin_amdgcn_sched_barrier(0);

    const unsigned short* abuf = lds[cur];
    const unsigned short* bbuf = abuf + 8192;
    __builtin_amdgcn_s_setprio(1);
    #pragma unroll
    for (int kk = 0; kk < 2; ++kk) {
      short8 af[4], bfr[4];
      #pragma unroll
      for (int mm = 0; mm < 4; ++mm) {
        int row = wr * 64 + mm * 16 + l15;
        int col = kk * 64 + g * 16;
        af[mm] = *(const short8*)((const char*)abuf + row * 128 + (col ^ ((row & 7) << 4)));
      }
      #pragma unroll
      for (int nn = 0; nn < 4; ++nn) {
        int row = wc * 64 + nn * 16 + l15;
        int col = kk * 64 + g * 16;
        bfr[nn] = *(const short8*)((const char*)bbuf + row * 128 + (col ^ ((row & 7) << 4)));
      }
      #pragma unroll
      for (int mm = 0; mm < 4; ++mm)
        #pragma unroll
        for (int nn = 0; nn < 4; ++nn)
          acc[mm][nn] = __builtin_amdgcn_mfma_f32_16x16x32_bf16(af[mm], bfr[nn], acc[mm][nn], 0, 0, 0);
    }
    __builtin_amdgcn_s_setprio(0);
    __builtin_amdgcn_sched_barrier(0);
    __builtin_amdgcn_s_barrier();
  }

  #pragma unroll
  for (int mm = 0; mm < 4; ++mm) {
    #pragma unroll
    for (int nn = 0; nn < 4; ++nn) {
      #pragma unroll
      for (int r = 0; r < 4; ++r) {
        int grow = bm * 128 + wr * 64 + mm * 16 + g * 4 + r;
        int gcol = bn * 256 + wc * 64 + nn * 16 + l15;
        size_t off = (size_t)grow * N + gcol;
        float v = acc[mm][nn][r];
        if (EPI == EPI_BF16) {
          Cb[off] = f2b(v);
        } else if (EPI == EPI_RESID) {
          Cf[off] = R[off] + v;
        } else if (EPI == EPI_SILU) {
          float s = 1.f / (1.f + __expf(-v));
          Cb[off] = f2b(v * s);
        } else {
          __builtin_nontemporal_store(v, &Cf[off]);
        }
      }
    }
  }
}

// ---------------------------------------------------------------- V transpose
__global__ void k_transpose_v(const unsigned short* __restrict__ v, int vstride,
                              unsigned short* __restrict__ vt) {
  __shared__ unsigned short tile[64][136];
  int pr = blockIdx.x >> 5;
  int st = blockIdx.x & 31;
  int bb = pr >> 4, h = pr & 15;
  int row = threadIdx.x >> 2;
  int cq = threadIdx.x & 3;
  const unsigned short* src =
      v + (size_t)(bb * SEQ + st * 64 + row) * vstride + h * HD + cq * 32;
  #pragma unroll
  for (int j = 0; j < 4; ++j)
    *(short8*)&tile[row][cq * 32 + j * 8] = *(const short8*)(src + j * 8);
  __syncthreads();
  int d = threadIdx.x >> 1;
  int sh = threadIdx.x & 1;
  unsigned short tmp[32];
  #pragma unroll
  for (int j = 0; j < 32; ++j) tmp[j] = tile[sh * 32 + j][d];
  unsigned short* dst = vt + ((size_t)pr * HD + d) * SEQ + st * 64 + sh * 32;
  #pragma unroll
  for (int j = 0; j < 4; ++j)
    *(short8*)(dst + j * 8) = *(const short8*)&tmp[j * 8];
}

// ---------------------------------------------------------------- attention
__launch_bounds__(256)
__global__ void k_attn(const unsigned short* __restrict__ q,
                       const unsigned short* __restrict__ k,
                       const unsigned short* __restrict__ vt,
                       unsigned short* __restrict__ ao, int qk_stride) {
  __shared__ unsigned short k_lds[64 * 128];
  __shared__ unsigned short vt_lds[128 * 64];
  __shared__ unsigned short p_lds[4][32 * 64];

  int bid = blockIdx.x;
  int pr = bid >> 4;
  int qt = 15 - (bid & 15);
  int bb = pr >> 4, h = pr & 15;
  int t = threadIdx.x, w = t >> 6, lane = t & 63;
  int g = lane >> 4, l15 = lane & 15;
  const float SCL = 0.08838834764831845f * 1.4426950408889634f;

  int qrow_base = qt * 128 + w * 32;
  short8 aq[2][4];
  #pragma unroll
  for (int mm = 0; mm < 2; ++mm) {
    size_t n = (size_t)(bb * SEQ + qrow_base + mm * 16 + l15);
    #pragma unroll
    for (int kk = 0; kk < 4; ++kk)
      aq[mm][kk] = *(const short8*)(q + n * qk_stride + h * HD + kk * 32 + g * 8);
  }

  f32x4 o[2][8] = {};
  float m2[2][4], ls[2][4];
  #pragma unroll
  for (int mm = 0; mm < 2; ++mm)
    #pragma unroll
    for (int r = 0; r < 4; ++r) { m2[mm][r] = -1e30f; ls[mm][r] = 0.f; }

  int nkv = 2 * qt + 2;
  for (int kvt = 0; kvt < nkv; ++kvt) {
    #pragma unroll
    for (int i = 0; i < 4; ++i) {
      int pos = ((i * 4 + w) << 10) + lane * 16;
      {
        int row = pos >> 8, csw = pos & 255;
        int csrc = csw ^ ((row & 7) << 4);
        gload16(k + (size_t)(bb * SEQ + kvt * 64 + row) * qk_stride + h * HD + (csrc >> 1),
                (char*)k_lds + ((i * 4 + w) << 10));
      }
      {
        int row = pos >> 7, csw = pos & 127;
        int csrc = csw ^ ((row & 7) << 4);
        gload16(vt + ((size_t)pr * HD + row) * SEQ + kvt * 64 + (csrc >> 1),
                (char*)vt_lds + ((i * 4 + w) << 10));
      }
    }
    __syncthreads();

    f32x4 s[2][4] = {};
    #pragma unroll
    for (int kk = 0; kk < 4; ++kk) {
      short8 bk[4];
      #pragma unroll
      for (int nn = 0; nn < 4; ++nn) {
        int row = nn * 16 + l15;
        int col = kk * 64 + g * 16;
        bk[nn] = *(const short8*)((const char*)k_lds + row * 256 + (col ^ ((row & 7) << 4)));
      }
      #pragma unroll
      for (int mm = 0; mm < 2; ++mm)
        #pragma unroll
        for (int nn = 0; nn < 4; ++nn)
          s[mm][nn] = __builtin_amdgcn_mfma_f32_16x16x32_bf16(aq[mm][kk], bk[nn], s[mm][nn], 0, 0, 0);
    }

    bool diag = (kvt >= 2 * qt);
    #pragma unroll
    for (int mm = 0; mm < 2; ++mm) {
      float mx[4] = {-1e30f, -1e30f, -1e30f, -1e30f};
      #pragma unroll
      for (int nn = 0; nn < 4; ++nn)
        #pragma unroll
        for (int r = 0; r < 4; ++r) {
          float sv = s[mm][nn][r] * SCL;
          if (diag) {
            int kvg = kvt * 64 + nn * 16 + l15;
            int qg = qrow_base + mm * 16 + g * 4 + r;
            if (kvg > qg) sv = -1e30f;
          }
          s[mm][nn][r] = sv;
          mx[r] = fmaxf(mx[r], sv);
        }
      #pragma unroll
      for (int r = 0; r < 4; ++r) {
        mx[r] = fmaxf(mx[r], __shfl_xor(mx[r], 1));
        mx[r] = fmaxf(mx[r], __shfl_xor(mx[r], 2));
        mx[r] = fmaxf(mx[r], __shfl_xor(mx[r], 4));
        mx[r] = fmaxf(mx[r], __shfl_xor(mx[r], 8));
        float mn = fmaxf(m2[mm][r], mx[r]);
        float al = exp2f(m2[mm][r] - mn);
        m2[mm][r] = mn;
        ls[mm][r] *= al;
        #pragma unroll
        for (int dd = 0; dd < 8; ++dd) o[mm][dd][r] *= al;
      }
      #pragma unroll
      for (int nn = 0; nn < 4; ++nn)
        #pragma unroll
        for (int r = 0; r < 4; ++r) {
          float pv = exp2f(s[mm][nn][r] - m2[mm][r]);
          ls[mm][r] += pv;
          int row = mm * 16 + g * 4 + r;
          int colb = (nn * 16 + l15) * 2;
          *(unsigned short*)((char*)p_lds[w] + row * 128 + (colb ^ (((row >> 1) & 7) << 4))) = f2b(pv);
        }
    }

    #pragma unroll
    for (int kk = 0; kk < 2; ++kk) {
      short8 pf[2], vf[8];
      #pragma unroll
      for (int mm = 0; mm < 2; ++mm) {
        int row = mm * 16 + l15;
        int col = kk * 64 + g * 16;
        pf[mm] = *(const short8*)((const char*)p_lds[w] + row * 128 + (col ^ (((row >> 1) & 7) << 4)));
      }
      #pragma unroll
      for (int dd = 0; dd < 8; ++dd) {
        int row = dd * 16 + l15;
        int col = kk * 64 + g * 16;
        vf[dd] = *(const short8*)((const char*)vt_lds + row * 128 + (col ^ ((row & 7) << 4)));
      }
      #pragma unroll
      for (int mm = 0; mm < 2; ++mm)
        #pragma unroll
        for (int dd = 0; dd < 8; ++dd)
          o[mm][dd] = __builtin_amdgcn_mfma_f32_16x16x32_bf16(pf[mm], vf[dd], o[mm][dd], 0, 0, 0);
    }
    __syncthreads();
  }

  #pragma unroll
  for (int mm = 0; mm < 2; ++mm) {
    float inv[4];
    #pragma unroll
    for (int r = 0; r < 4; ++r) {
      float tt = ls[mm][r];
      tt += __shfl_xor(tt, 1);
      tt += __shfl_xor(tt, 2);
      tt += __shfl_xor(tt, 4);
      tt += __shfl_xor(tt, 8);
      inv[r] = 1.f / tt;
    }
    #pragma unroll
    for (int dd = 0; dd < 8; ++dd)
      #pragma unroll
      for (int r = 0; r < 4; ++r) {
        size_t n = (size_t)(bb * SEQ + qrow_base + mm * 16 + g * 4 + r);
        int col = h * HD + dd * 16 + l15;
        ao[n * DM + col] = f2b(o[mm][dd][r] * inv[r]);
      }
  }
}

// ---------------------------------------------------------------- launch
extern "C" void kernel_launch(void* const* d_in, const int* in_sizes, int n_in,
                              void* d_out, int out_size, void* d_ws, size_t ws_size,
                              hipStream_t stream) {
  const int* tokens = (const int*)d_in[0];
  const float* tok_emb = (const float*)d_in[1];
  const float* wq = (const float*)d_in[2];
  const float* wk = (const float*)d_in[3];
  const float* wv = (const float*)d_in[4];
  const float* wo = (const float*)d_in[5];
  const float* attn_nw = (const float*)d_in[6];
  const float* ffn_nw = (const float*)d_in[7];
  const float* final_nw = (const float*)d_in[8];
  const float* w1 = (const float*)d_in[9];
  const float* w2 = (const float*)d_in[10];
  const float* out_proj = (const float*)d_in[11];
  float* out = (float*)d_out;

  char* ws = (char*)d_ws;
  size_t off = 0;
  auto alloc = [&](size_t bytes) -> char* {
    char* p = ws + off;
    off += (bytes + 255) & ~(size_t)255;
    return p;
  };
  unsigned short* wqkv_b = (unsigned short*)alloc((size_t)3 * DM * DM * 2);
  unsigned short* wo_b = (unsigned short*)alloc((size_t)DM * DM * 2);
  unsigned short* w1_b = (unsigned short*)alloc((size_t)DFF * DM * 2);
  unsigned short* w2_b = (unsigned short*)alloc((size_t)DM * DFF * 2);
  unsigned short* wop_b = (unsigned short*)alloc((size_t)NVOCAB * DM * 2);
  float* x = (float*)alloc((size_t)NTOK * DM * 4);
  unsigned short* xn = (unsigned short*)alloc((size_t)NTOK * DM * 2);
  unsigned short* qkv_b = (unsigned short*)alloc((size_t)NTOK * 3 * DM * 2);
  unsigned short* vt_b = (unsigned short*)alloc((size_t)NTOK * DM * 2);
  unsigned short* ao_b = (unsigned short*)alloc((size_t)NTOK * DM * 2);
  unsigned short* h1_b = qkv_b;  // alias: qkv+vt dead when h1 written

  auto conv = [&](const float* src, unsigned short* dst, size_t n) {
    int nq = (int)(n / 4);
    int grid = (nq + 255) / 256;
    if (grid > 4096) grid = 4096;
    k_f32_to_bf16<<<grid, 256, 0, stream>>>(src, dst, nq);
  };
  conv(wq, wqkv_b, (size_t)DM * DM);
  conv(wk, wqkv_b + (size_t)DM * DM, (size_t)DM * DM);
  conv(wv, wqkv_b + (size_t)2 * DM * DM, (size_t)DM * DM);
  conv(wo, wo_b, (size_t)DM * DM);
  conv(w1, w1_b, (size_t)DFF * DM);
  conv(w2, w2_b, (size_t)DM * DFF);
  conv(out_proj, wop_b, (size_t)NVOCAB * DM);

  k_embed<<<NTOK, 256, 0, stream>>>(tokens, tok_emb, x);
  k_rmsnorm<<<NTOK, 256, 0, stream>>>(x, attn_nw, xn);

  // fused QKV: [4096, 6144]
  k_gemm8p<EPI_BF16><<<(NTOK / 256) * (3 * DM / 256), 512, 0, stream>>>(
      xn, wqkv_b, NTOK, 3 * DM, DM, 3 * DM / 256, nullptr, qkv_b, nullptr);

  k_transpose_v<<<32 * 32, 256, 0, stream>>>(qkv_b + 2 * DM, 3 * DM, vt_b);
  k_attn<<<32 * 16, 256, 0, stream>>>(qkv_b, qkv_b + DM, vt_b, ao_b, 3 * DM);

  k_gemm_sm<EPI_RESID><<<(NTOK / 128) * (DM / 256), 512, 0, stream>>>(
      ao_b, wo_b, NTOK, DM, DM, x, nullptr, x);

  k_rmsnorm<<<NTOK, 256, 0, stream>>>(x, ffn_nw, xn);
  k_gemm8p<EPI_SILU><<<(NTOK / 256) * (DFF / 256), 512, 0, stream>>>(
      xn, w1_b, NTOK, DFF, DM, DFF / 256, nullptr, h1_b, nullptr);
  k_gemm_sm<EPI_RESID><<<(NTOK / 128) * (DM / 256), 512, 0, stream>>>(
      h1_b, w2_b, NTOK, DM, DFF, x, nullptr, x);

  k_rmsnorm<<<NTOK, 256, 0, stream>>>(x, final_nw, xn);
  // logits: GN=25 -> B group 26MB L3-resident; nt-stores keep C out of L3
  k_gemm8p<EPI_F32><<<(NTOK / 256) * (NVOCAB / 256), 512, 0, stream>>>(
      xn, wop_b, NTOK, NVOCAB, DM, 25, out, nullptr, nullptr);
}

// Round 8
// 1307.507 us; speedup vs baseline: 1.4017x; 1.0065x over previous
//
#include <hip/hip_runtime.h>
#include <stdint.h>

#define DM     2048
#define NHE    16
#define DFF    8192
#define NBATCH 2
#define SEQ    2048
#define NTOK   4096
#define HD     128
#define NVOCAB 32000

typedef __attribute__((ext_vector_type(8))) short short8;
typedef __attribute__((ext_vector_type(4))) float f32x4;
typedef __attribute__((ext_vector_type(4))) unsigned short u16x4;

static __device__ __forceinline__ unsigned short f2b(float f) {
  union { float f; uint32_t u; } v; v.f = f;
  return (unsigned short)((v.u + 0x7FFFu + ((v.u >> 16) & 1u)) >> 16);
}

static __device__ __forceinline__ void gload16(const void* g, void* l) {
  __builtin_amdgcn_global_load_lds(
      (const __attribute__((address_space(1))) unsigned int*)g,
      (__attribute__((address_space(3))) unsigned int*)l, 16, 0, 0);
}

// ---------------------------------------------------------------- conversions
__global__ void k_f32_to_bf16(const float* __restrict__ in,
                              unsigned short* __restrict__ out, int nq) {
  int i = blockIdx.x * blockDim.x + threadIdx.x;
  int stride = gridDim.x * blockDim.x;
  for (; i < nq; i += stride) {
    float4 v = ((const float4*)in)[i];
    u16x4 o;
    o.x = f2b(v.x); o.y = f2b(v.y); o.z = f2b(v.z); o.w = f2b(v.w);
    ((u16x4*)out)[i] = o;
  }
}

// ---------------------------------------------------------------- embedding
__global__ void k_embed(const int* __restrict__ tok,
                        const float* __restrict__ emb, float* __restrict__ x) {
  int n = blockIdx.x;
  int t = tok[n];
  const float4* src = (const float4*)(emb + (size_t)t * DM);
  float4* dst = (float4*)(x + (size_t)n * DM);
  for (int i = threadIdx.x; i < DM / 4; i += blockDim.x) dst[i] = src[i];
}

// ---------------------------------------------------------------- rmsnorm
__global__ void k_rmsnorm(const float* __restrict__ x, const float* __restrict__ wt,
                          unsigned short* __restrict__ out) {
  int n = blockIdx.x;
  const float* row = x + (size_t)n * DM;
  float ss = 0.f;
  #pragma unroll
  for (int it = 0; it < 2; ++it) {
    int i = threadIdx.x * 4 + it * 1024;
    float4 v = *(const float4*)(row + i);
    ss += v.x * v.x + v.y * v.y + v.z * v.z + v.w * v.w;
  }
  #pragma unroll
  for (int m = 1; m < 64; m <<= 1) ss += __shfl_xor(ss, m);
  __shared__ float p[4];
  if ((threadIdx.x & 63) == 0) p[threadIdx.x >> 6] = ss;
  __syncthreads();
  float inv = rsqrtf((p[0] + p[1] + p[2] + p[3]) * (1.f / DM) + 1e-6f);
  #pragma unroll
  for (int it = 0; it < 2; ++it) {
    int i = threadIdx.x * 4 + it * 1024;
    float4 v = *(const float4*)(row + i);
    float4 w4 = *(const float4*)(wt + i);
    u16x4 o;
    o.x = f2b(v.x * w4.x * inv); o.y = f2b(v.y * w4.y * inv);
    o.z = f2b(v.z * w4.z * inv); o.w = f2b(v.w * w4.w * inv);
    *(u16x4*)(out + (size_t)n * DM + i) = o;
  }
}

#define EPI_BF16  0
#define EPI_RESID 1
#define EPI_SILU  2
#define EPI_F32   3

// ---------------------------------------------------------------- GEMM 256x256 4-phase pipelined
// C[M,N] = A[M,K]*B[N,K]^T. 8 waves (2M x 4N), per-wave 128x64, BK=64.
// Double-buffered 128KB LDS. Per K-tile 4 phases; stage counts [5,1,1,1]
// (B-full + A-quad0 at phase0; A-quad q at phase q). Counted vmcnt [7,7,7,3]
// publishes each staged load exactly at its consumer's preceding barrier
// (in-order vmcnt retirement). One iteration-end barrier = WAR guard.
// Block order: DISPATCH-ORDER grouping — bm-fastest within a GN-wide bn
// group: 16 concurrent bids share one B-tile (1 HBM fetch + L3 hits),
// A stays L3-resident. No XCD pre-swizzle (it destroys window locality).
#define PHASE(Q, VM)                                                          \
  {                                                                           \
    short8 af[2][2];                                                          \
    _Pragma("unroll")                                                         \
    for (int mi = 0; mi < 2; ++mi)                                            \
      _Pragma("unroll")                                                       \
      for (int kk = 0; kk < 2; ++kk) {                                        \
        int row = wr * 128 + (2 * (Q) + mi) * 16 + l15;                       \
        int col = kk * 64 + g * 16;                                           \
        af[mi][kk] = *(const short8*)((const char*)abuf + row * 128 +         \
                                      (col ^ ((row & 7) << 4)));              \
      }                                                                       \
    if ((Q) == 0) {                                                           \
      _Pragma("unroll")                                                       \
      for (int nn = 0; nn < 4; ++nn)                                          \
        _Pragma("unroll")                                                     \
        for (int kk = 0; kk < 2; ++kk) {                                      \
          int row = wc * 64 + nn * 16 + l15;                                  \
          int col = kk * 64 + g * 16;                                         \
          bfr[nn][kk] = *(const short8*)((const char*)bbuf + row * 128 +      \
                                         (col ^ ((row & 7) << 4)));           \
        }                                                                     \
    }                                                                         \
    if (kt + 1 < nkt) {                                                       \
      if ((Q) == 0) {                                                         \
        _Pragma("unroll")                                                     \
        for (int i = 0; i < 4; ++i) {                                         \
          int pos = (i * 512 + t) << 4;                                       \
          int row = pos >> 7, colb = pos & 127;                               \
          int csrc = colb ^ ((row & 7) << 4);                                 \
          gload16(Bm + bbase + (size_t)row * K + k0n + (csrc >> 1),           \
                  (char*)(nbuf + 16384) + pos);                               \
        }                                                                     \
      }                                                                       \
      {                                                                       \
        int pos = (t < 256) ? ((Q) * 4096 + t * 16)                           \
                            : (16384 + (Q) * 4096 + (t - 256) * 16);          \
        int row = pos >> 7, colb = pos & 127;                                 \
        int csrc = colb ^ ((row & 7) << 4);                                   \
        gload16(A + abase + (size_t)row * K + k0n + (csrc >> 1),              \
                (char*)nbuf + pos);                                           \
      }                                                                       \
      asm volatile("s_waitcnt vmcnt(" VM ")" ::: "memory");                   \
    } else {                                                                  \
      if ((Q) == 0) asm volatile("s_waitcnt vmcnt(0)" ::: "memory");          \
    }                                                                         \
    __builtin_amdgcn_s_barrier();                                             \
    asm volatile("s_waitcnt lgkmcnt(0)" ::: "memory");                        \
    __builtin_amdgcn_sched_barrier(0);                                        \
    __builtin_amdgcn_s_setprio(1);                                            \
    _Pragma("unroll")                                                         \
    for (int mi = 0; mi < 2; ++mi)                                            \
      _Pragma("unroll")                                                       \
      for (int nn = 0; nn < 4; ++nn)                                          \
        _Pragma("unroll")                                                     \
        for (int kk = 0; kk < 2; ++kk)                                        \
          acc[2 * (Q) + mi][nn] = __builtin_amdgcn_mfma_f32_16x16x32_bf16(    \
              af[mi][kk], bfr[nn][kk], acc[2 * (Q) + mi][nn], 0, 0, 0);       \
    __builtin_amdgcn_s_setprio(0);                                            \
    __builtin_amdgcn_sched_barrier(0);                                        \
  }

template <int EPI>
__launch_bounds__(512, 2)
__global__ void k_gemm8p(const unsigned short* __restrict__ A,
                         const unsigned short* __restrict__ Bm,
                         int M, int N, int K, int GN,
                         float* __restrict__ Cf, unsigned short* __restrict__ Cb,
                         const float* __restrict__ R) {
  __shared__ unsigned short lds[2][32768];   // per buf: A 32KB + B 32KB
  int nbm = M >> 8;
  int b = blockIdx.x;                        // dispatch order = concurrency order
  int grpsz = nbm * GN;
  int gg = b / grpsz, rr = b % grpsz;
  int bm = rr % nbm;                         // bm-fastest: 16 consecutive bids
  int bn = gg * GN + rr / nbm;               //   share one B-tile via L3
  int t = threadIdx.x, w = t >> 6, lane = t & 63;
  int wr = w >> 2, wc = w & 3;
  int g = lane >> 4, l15 = lane & 15;

  f32x4 acc[8][4] = {};
  size_t abase = (size_t)(bm * 256) * K;
  size_t bbase = (size_t)(bn * 256) * K;
  int nkt = K >> 6;

  // prologue: stage tile 0 fully (A 32KB + B 32KB), drain, barrier
  {
    unsigned short* nbuf = lds[0];
    #pragma unroll
    for (int i = 0; i < 4; ++i) {
      int pos = (i * 512 + t) << 4;
      int row = pos >> 7, colb = pos & 127;
      int csrc = colb ^ ((row & 7) << 4);
      gload16(Bm + bbase + (size_t)row * K + (csrc >> 1), (char*)(nbuf + 16384) + pos);
    }
    #pragma unroll
    for (int i = 0; i < 4; ++i) {
      int pos = (i * 512 + t) << 4;
      int row = pos >> 7, colb = pos & 127;
      int csrc = colb ^ ((row & 7) << 4);
      gload16(A + abase + (size_t)row * K + (csrc >> 1), (char*)nbuf + pos);
    }
    asm volatile("s_waitcnt vmcnt(0)" ::: "memory");
    __builtin_amdgcn_s_barrier();
  }

  for (int kt = 0; kt < nkt; ++kt) {
    int cur = kt & 1;
    const unsigned short* abuf = lds[cur];
    const unsigned short* bbuf = abuf + 16384;
    unsigned short* nbuf = lds[1 - cur];
    int k0n = (kt + 1) << 6;
    short8 bfr[4][2];
    PHASE(0, "7")
    PHASE(1, "7")
    PHASE(2, "7")
    PHASE(3, "3")
    __builtin_amdgcn_s_barrier();            // iteration-end WAR guard
  }

  #pragma unroll
  for (int mm = 0; mm < 8; ++mm) {
    #pragma unroll
    for (int nn = 0; nn < 4; ++nn) {
      #pragma unroll
      for (int r = 0; r < 4; ++r) {
        int grow = bm * 256 + wr * 128 + mm * 16 + g * 4 + r;
        int gcol = bn * 256 + wc * 64 + nn * 16 + l15;
        size_t off = (size_t)grow * N + gcol;
        float v = acc[mm][nn][r];
        if (EPI == EPI_BF16) {
          Cb[off] = f2b(v);
        } else if (EPI == EPI_RESID) {
          Cf[off] = R[off] + v;
        } else if (EPI == EPI_SILU) {
          float s = 1.f / (1.f + __expf(-v));
          Cb[off] = f2b(v * s);
        } else {
          Cf[off] = v;
        }
      }
    }
  }
}

// ---------------------------------------------------------------- GEMM 128x256 simple (r4-style)
template <int EPI>
__launch_bounds__(512, 2)
__global__ void k_gemm_sm(const unsigned short* __restrict__ A,
                          const unsigned short* __restrict__ Bm,
                          int M, int N, int K,
                          float* __restrict__ Cf, unsigned short* __restrict__ Cb,
                          const float* __restrict__ R) {
  __shared__ unsigned short lds[2][24576];   // per buf: A 16KB + B 32KB
  int nbn = N >> 8;
  int nwg = gridDim.x;
  int bid = blockIdx.x;
  int cpx = nwg >> 3;
  bid = (bid & 7) * cpx + (bid >> 3);
  int bm = bid / nbn, bn = bid % nbn;
  int t = threadIdx.x, w = t >> 6, lane = t & 63;
  int wr = w >> 2, wc = w & 3;               // 2 (M) x 4 (N)
  int g = lane >> 4, l15 = lane & 15;

  f32x4 acc[4][4] = {};
  size_t abase = (size_t)(bm * 128) * K;
  size_t bbase = (size_t)(bn * 256) * K;
  int nkt = K >> 6;

  auto stage = [&](int buf, int kt) {
    unsigned short* dst = lds[buf];
    int k0 = kt << 6;
    #pragma unroll
    for (int i = 0; i < 2; ++i) {
      int pos = (i * 512 + t) << 4;
      int row = pos >> 7, colb = pos & 127;
      int csrc = colb ^ ((row & 7) << 4);
      gload16(A + abase + (size_t)row * K + k0 + (csrc >> 1), (char*)dst + pos);
    }
    #pragma unroll
    for (int i = 0; i < 4; ++i) {
      int pos = (i * 512 + t) << 4;
      int row = pos >> 7, colb = pos & 127;
      int csrc = colb ^ ((row & 7) << 4);
      gload16(Bm + bbase + (size_t)row * K + k0 + (csrc >> 1),
              (char*)(dst + 8192) + pos);
    }
  };

  stage(0, 0);
  for (int kt = 0; kt < nkt; ++kt) {
    int cur = kt & 1;
    if (kt + 1 < nkt) {
      stage(1 - cur, kt + 1);
      asm volatile("s_waitcnt vmcnt(6)" ::: "memory");
    } else {
      asm volatile("s_waitcnt vmcnt(0)" ::: "memory");
    }
    __builtin_amdgcn_s_barrier();
    __builtin_amdgcn_sched_barrier(0);

    const unsigned short* abuf = lds[cur];
    const unsigned short* bbuf = abuf + 8192;
    __builtin_amdgcn_s_setprio(1);
    #pragma unroll
    for (int kk = 0; kk < 2; ++kk) {
      short8 af[4], bfr[4];
      #pragma unroll
      for (int mm = 0; mm < 4; ++mm) {
        int row = wr * 64 + mm * 16 + l15;
        int col = kk * 64 + g * 16;
        af[mm] = *(const short8*)((const char*)abuf + row * 128 + (col ^ ((row & 7) << 4)));
      }
      #pragma unroll
      for (int nn = 0; nn < 4; ++nn) {
        int row = wc * 64 + nn * 16 + l15;
        int col = kk * 64 + g * 16;
        bfr[nn] = *(const short8*)((const char*)bbuf + row * 128 + (col ^ ((row & 7) << 4)));
      }
      #pragma unroll
      for (int mm = 0; mm < 4; ++mm)
        #pragma unroll
        for (int nn = 0; nn < 4; ++nn)
          acc[mm][nn] = __builtin_amdgcn_mfma_f32_16x16x32_bf16(af[mm], bfr[nn], acc[mm][nn], 0, 0, 0);
    }
    __builtin_amdgcn_s_setprio(0);
    __builtin_amdgcn_sched_barrier(0);
    __builtin_amdgcn_s_barrier();
  }

  #pragma unroll
  for (int mm = 0; mm < 4; ++mm) {
    #pragma unroll
    for (int nn = 0; nn < 4; ++nn) {
      #pragma unroll
      for (int r = 0; r < 4; ++r) {
        int grow = bm * 128 + wr * 64 + mm * 16 + g * 4 + r;
        int gcol = bn * 256 + wc * 64 + nn * 16 + l15;
        size_t off = (size_t)grow * N + gcol;
        float v = acc[mm][nn][r];
        if (EPI == EPI_BF16) {
          Cb[off] = f2b(v);
        } else if (EPI == EPI_RESID) {
          Cf[off] = R[off] + v;
        } else if (EPI == EPI_SILU) {
          float s = 1.f / (1.f + __expf(-v));
          Cb[off] = f2b(v * s);
        } else {
          Cf[off] = v;
        }
      }
    }
  }
}

// ---------------------------------------------------------------- V transpose
__global__ void k_transpose_v(const unsigned short* __restrict__ v, int vstride,
                              unsigned short* __restrict__ vt) {
  __shared__ unsigned short tile[64][136];
  int pr = blockIdx.x >> 5;
  int st = blockIdx.x & 31;
  int bb = pr >> 4, h = pr & 15;
  int row = threadIdx.x >> 2;
  int cq = threadIdx.x & 3;
  const unsigned short* src =
      v + (size_t)(bb * SEQ + st * 64 + row) * vstride + h * HD + cq * 32;
  #pragma unroll
  for (int j = 0; j < 4; ++j)
    *(short8*)&tile[row][cq * 32 + j * 8] = *(const short8*)(src + j * 8);
  __syncthreads();
  int d = threadIdx.x >> 1;
  int sh = threadIdx.x & 1;
  unsigned short tmp[32];
  #pragma unroll
  for (int j = 0; j < 32; ++j) tmp[j] = tile[sh * 32 + j][d];
  unsigned short* dst = vt + ((size_t)pr * HD + d) * SEQ + st * 64 + sh * 32;
  #pragma unroll
  for (int j = 0; j < 4; ++j)
    *(short8*)(dst + j * 8) = *(const short8*)&tmp[j * 8];
}

// ---------------------------------------------------------------- attention
__launch_bounds__(256)
__global__ void k_attn(const unsigned short* __restrict__ q,
                       const unsigned short* __restrict__ k,
                       const unsigned short* __restrict__ vt,
                       unsigned short* __restrict__ ao, int qk_stride) {
  __shared__ unsigned short k_lds[64 * 128];
  __shared__ unsigned short vt_lds[128 * 64];
  __shared__ unsigned short p_lds[4][32 * 64];

  int bid = blockIdx.x;
  int pr = bid >> 4;
  int qt = 15 - (bid & 15);
  int bb = pr >> 4, h = pr & 15;
  int t = threadIdx.x, w = t >> 6, lane = t & 63;
  int g = lane >> 4, l15 = lane & 15;
  const float SCL = 0.08838834764831845f * 1.4426950408889634f;

  int qrow_base = qt * 128 + w * 32;
  short8 aq[2][4];
  #pragma unroll
  for (int mm = 0; mm < 2; ++mm) {
    size_t n = (size_t)(bb * SEQ + qrow_base + mm * 16 + l15);
    #pragma unroll
    for (int kk = 0; kk < 4; ++kk)
      aq[mm][kk] = *(const short8*)(q + n * qk_stride + h * HD + kk * 32 + g * 8);
  }

  f32x4 o[2][8] = {};
  float m2[2][4], ls[2][4];
  #pragma unroll
  for (int mm = 0; mm < 2; ++mm)
    #pragma unroll
    for (int r = 0; r < 4; ++r) { m2[mm][r] = -1e30f; ls[mm][r] = 0.f; }

  int nkv = 2 * qt + 2;
  for (int kvt = 0; kvt < nkv; ++kvt) {
    #pragma unroll
    for (int i = 0; i < 4; ++i) {
      int pos = ((i * 4 + w) << 10) + lane * 16;
      {
        int row = pos >> 8, csw = pos & 255;
        int csrc = csw ^ ((row & 7) << 4);
        gload16(k + (size_t)(bb * SEQ + kvt * 64 + row) * qk_stride + h * HD + (csrc >> 1),
                (char*)k_lds + ((i * 4 + w) << 10));
      }
      {
        int row = pos >> 7, csw = pos & 127;
        int csrc = csw ^ ((row & 7) << 4);
        gload16(vt + ((size_t)pr * HD + row) * SEQ + kvt * 64 + (csrc >> 1),
                (char*)vt_lds + ((i * 4 + w) << 10));
      }
    }
    __syncthreads();

    f32x4 s[2][4] = {};
    #pragma unroll
    for (int kk = 0; kk < 4; ++kk) {
      short8 bk[4];
      #pragma unroll
      for (int nn = 0; nn < 4; ++nn) {
        int row = nn * 16 + l15;
        int col = kk * 64 + g * 16;
        bk[nn] = *(const short8*)((const char*)k_lds + row * 256 + (col ^ ((row & 7) << 4)));
      }
      #pragma unroll
      for (int mm = 0; mm < 2; ++mm)
        #pragma unroll
        for (int nn = 0; nn < 4; ++nn)
          s[mm][nn] = __builtin_amdgcn_mfma_f32_16x16x32_bf16(aq[mm][kk], bk[nn], s[mm][nn], 0, 0, 0);
    }

    bool diag = (kvt >= 2 * qt);
    #pragma unroll
    for (int mm = 0; mm < 2; ++mm) {
      float mx[4] = {-1e30f, -1e30f, -1e30f, -1e30f};
      #pragma unroll
      for (int nn = 0; nn < 4; ++nn)
        #pragma unroll
        for (int r = 0; r < 4; ++r) {
          float sv = s[mm][nn][r] * SCL;
          if (diag) {
            int kvg = kvt * 64 + nn * 16 + l15;
            int qg = qrow_base + mm * 16 + g * 4 + r;
            if (kvg > qg) sv = -1e30f;
          }
          s[mm][nn][r] = sv;
          mx[r] = fmaxf(mx[r], sv);
        }
      #pragma unroll
      for (int r = 0; r < 4; ++r) {
        mx[r] = fmaxf(mx[r], __shfl_xor(mx[r], 1));
        mx[r] = fmaxf(mx[r], __shfl_xor(mx[r], 2));
        mx[r] = fmaxf(mx[r], __shfl_xor(mx[r], 4));
        mx[r] = fmaxf(mx[r], __shfl_xor(mx[r], 8));
        float mn = fmaxf(m2[mm][r], mx[r]);
        float al = exp2f(m2[mm][r] - mn);
        m2[mm][r] = mn;
        ls[mm][r] *= al;
        #pragma unroll
        for (int dd = 0; dd < 8; ++dd) o[mm][dd][r] *= al;
      }
      #pragma unroll
      for (int nn = 0; nn < 4; ++nn)
        #pragma unroll
        for (int r = 0; r < 4; ++r) {
          float pv = exp2f(s[mm][nn][r] - m2[mm][r]);
          ls[mm][r] += pv;
          int row = mm * 16 + g * 4 + r;
          int colb = (nn * 16 + l15) * 2;
          *(unsigned short*)((char*)p_lds[w] + row * 128 + (colb ^ (((row >> 1) & 7) << 4))) = f2b(pv);
        }
    }

    #pragma unroll
    for (int kk = 0; kk < 2; ++kk) {
      short8 pf[2], vf[8];
      #pragma unroll
      for (int mm = 0; mm < 2; ++mm) {
        int row = mm * 16 + l15;
        int col = kk * 64 + g * 16;
        pf[mm] = *(const short8*)((const char*)p_lds[w] + row * 128 + (col ^ (((row >> 1) & 7) << 4)));
      }
      #pragma unroll
      for (int dd = 0; dd < 8; ++dd) {
        int row = dd * 16 + l15;
        int col = kk * 64 + g * 16;
        vf[dd] = *(const short8*)((const char*)vt_lds + row * 128 + (col ^ ((row & 7) << 4)));
      }
      #pragma unroll
      for (int mm = 0; mm < 2; ++mm)
        #pragma unroll
        for (int dd = 0; dd < 8; ++dd)
          o[mm][dd] = __builtin_amdgcn_mfma_f32_16x16x32_bf16(pf[mm], vf[dd], o[mm][dd], 0, 0, 0);
    }
    __syncthreads();
  }

  #pragma unroll
  for (int mm = 0; mm < 2; ++mm) {
    float inv[4];
    #pragma unroll
    for (int r = 0; r < 4; ++r) {
      float tt = ls[mm][r];
      tt += __shfl_xor(tt, 1);
      tt += __shfl_xor(tt, 2);
      tt += __shfl_xor(tt, 4);
      tt += __shfl_xor(tt, 8);
      inv[r] = 1.f / tt;
    }
    #pragma unroll
    for (int dd = 0; dd < 8; ++dd)
      #pragma unroll
      for (int r = 0; r < 4; ++r) {
        size_t n = (size_t)(bb * SEQ + qrow_base + mm * 16 + g * 4 + r);
        int col = h * HD + dd * 16 + l15;
        ao[n * DM + col] = f2b(o[mm][dd][r] * inv[r]);
      }
  }
}

// ---------------------------------------------------------------- launch
extern "C" void kernel_launch(void* const* d_in, const int* in_sizes, int n_in,
                              void* d_out, int out_size, void* d_ws, size_t ws_size,
                              hipStream_t stream) {
  const int* tokens = (const int*)d_in[0];
  const float* tok_emb = (const float*)d_in[1];
  const float* wq = (const float*)d_in[2];
  const float* wk = (const float*)d_in[3];
  const float* wv = (const float*)d_in[4];
  const float* wo = (const float*)d_in[5];
  const float* attn_nw = (const float*)d_in[6];
  const float* ffn_nw = (const float*)d_in[7];
  const float* final_nw = (const float*)d_in[8];
  const float* w1 = (const float*)d_in[9];
  const float* w2 = (const float*)d_in[10];
  const float* out_proj = (const float*)d_in[11];
  float* out = (float*)d_out;

  char* ws = (char*)d_ws;
  size_t off = 0;
  auto alloc = [&](size_t bytes) -> char* {
    char* p = ws + off;
    off += (bytes + 255) & ~(size_t)255;
    return p;
  };
  unsigned short* wqkv_b = (unsigned short*)alloc((size_t)3 * DM * DM * 2);
  unsigned short* wo_b = (unsigned short*)alloc((size_t)DM * DM * 2);
  unsigned short* w1_b = (unsigned short*)alloc((size_t)DFF * DM * 2);
  unsigned short* w2_b = (unsigned short*)alloc((size_t)DM * DFF * 2);
  unsigned short* wop_b = (unsigned short*)alloc((size_t)NVOCAB * DM * 2);
  float* x = (float*)alloc((size_t)NTOK * DM * 4);
  unsigned short* xn = (unsigned short*)alloc((size_t)NTOK * DM * 2);
  unsigned short* qkv_b = (unsigned short*)alloc((size_t)NTOK * 3 * DM * 2);
  unsigned short* vt_b = (unsigned short*)alloc((size_t)NTOK * DM * 2);
  unsigned short* ao_b = (unsigned short*)alloc((size_t)NTOK * DM * 2);
  unsigned short* h1_b = qkv_b;  // alias: qkv+vt dead when h1 written

  auto conv = [&](const float* src, unsigned short* dst, size_t n) {
    int nq = (int)(n / 4);
    int grid = (nq + 255) / 256;
    if (grid > 4096) grid = 4096;
    k_f32_to_bf16<<<grid, 256, 0, stream>>>(src, dst, nq);
  };
  conv(wq, wqkv_b, (size_t)DM * DM);
  conv(wk, wqkv_b + (size_t)DM * DM, (size_t)DM * DM);
  conv(wv, wqkv_b + (size_t)2 * DM * DM, (size_t)DM * DM);
  conv(wo, wo_b, (size_t)DM * DM);
  conv(w1, w1_b, (size_t)DFF * DM);
  conv(w2, w2_b, (size_t)DM * DFF);
  conv(out_proj, wop_b, (size_t)NVOCAB * DM);

  k_embed<<<NTOK, 256, 0, stream>>>(tokens, tok_emb, x);
  k_rmsnorm<<<NTOK, 256, 0, stream>>>(x, attn_nw, xn);

  // fused QKV: [4096, 6144] — single group (B 25MB L3-resident), bm-fastest
  k_gemm8p<EPI_BF16><<<(NTOK / 256) * (3 * DM / 256), 512, 0, stream>>>(
      xn, wqkv_b, NTOK, 3 * DM, DM, 3 * DM / 256, nullptr, qkv_b, nullptr);

  k_transpose_v<<<32 * 32, 256, 0, stream>>>(qkv_b + 2 * DM, 3 * DM, vt_b);
  k_attn<<<32 * 16, 256, 0, stream>>>(qkv_b, qkv_b + DM, vt_b, ao_b, 3 * DM);

  k_gemm_sm<EPI_RESID><<<(NTOK / 128) * (DM / 256), 512, 0, stream>>>(
      ao_b, wo_b, NTOK, DM, DM, x, nullptr, x);

  k_rmsnorm<<<NTOK, 256, 0, stream>>>(x, ffn_nw, xn);
  // FFN1: single group (B 34MB), bm-fastest
  k_gemm8p<EPI_SILU><<<(NTOK / 256) * (DFF / 256), 512, 0, stream>>>(
      xn, w1_b, NTOK, DFF, DM, DFF / 256, nullptr, h1_b, nullptr);
  k_gemm_sm<EPI_RESID><<<(NTOK / 128) * (DM / 256), 512, 0, stream>>>(
      h1_b, w2_b, NTOK, DM, DFF, x, nullptr, x);

  k_rmsnorm<<<NTOK, 256, 0, stream>>>(x, final_nw, xn);
  // logits: GN=25 -> dispatch-window B working set ~26-32MB, L3-resident
  k_gemm8p<EPI_F32><<<(NTOK / 256) * (NVOCAB / 256), 512, 0, stream>>>(
      xn, wop_b, NTOK, NVOCAB, DM, 25, out, nullptr, nullptr);
}